// Round 1
// baseline (1162.457 us; speedup 1.0000x reference)
//
#include <hip/hip_runtime.h>
#include <hip/hip_bf16.h>
#include <math.h>

typedef short s16x8 __attribute__((ext_vector_type(8)));
typedef float f32x4 __attribute__((ext_vector_type(4)));

#define DIM 768
#define HEADS 12

static __device__ __forceinline__ short f2bf(float x) {
    union { float f; unsigned u; } v; v.f = x;
    unsigned r = (v.u + 0x7FFF + ((v.u >> 16) & 1)) >> 16;
    return (short)r;
}
static __device__ __forceinline__ float bf2f(short x) {
    union { unsigned u; float f; } v;
    v.u = ((unsigned)(unsigned short)x) << 16;
    return v.f;
}

// partitioned token t (win*512+n) -> natural token index in [0, 8192)
static __device__ __forceinline__ int nat_row(int t) {
    int w = t >> 9, n = t & 511;
    int b = w >> 3, dO = (w >> 2) & 1, hO = (w >> 1) & 1, wO = w & 1;
    int di = n >> 6, hi = (n >> 3) & 7, wi = n & 7;
    int Dd = dO * 8 + di, Hh = hO * 8 + hi, Ww = wO * 8 + wi;
    return ((b * 16 + Dd) * 16 + Hh) * 16 + Ww;
}

// ---------------- weight transpose + fp32->bf16 ----------------
__global__ __launch_bounds__(256) void transpose_cvt(
    const float* __restrict__ in, short* __restrict__ out, int K, int N) {
    __shared__ float tile[32][33];
    int n0 = blockIdx.x * 32, k0 = blockIdx.y * 32;
    int tx = threadIdx.x & 31, ty = threadIdx.x >> 5;
    for (int j = 0; j < 4; j++) {
        int r = ty + j * 8;
        tile[r][tx] = in[(size_t)(k0 + r) * N + n0 + tx];
    }
    __syncthreads();
    for (int j = 0; j < 4; j++) {
        int r = ty + j * 8;
        out[(size_t)(n0 + r) * K + k0 + tx] = f2bf(tile[tx][r]);
    }
}

// ---------------- layernorm (PART=1: window-partition remap of input row) ----
template<int PART>
__global__ __launch_bounds__(256) void ln_kernel(
    const float* __restrict__ x, const float* __restrict__ gw,
    const float* __restrict__ gb, short* __restrict__ out) {
    int t = blockIdx.x;
    int row = PART ? nat_row(t) : t;
    const float* xr = x + (size_t)row * DIM;
    float v0 = xr[threadIdx.x], v1 = xr[threadIdx.x + 256], v2 = xr[threadIdx.x + 512];
    float s1 = v0 + v1 + v2;
    float s2 = v0 * v0 + v1 * v1 + v2 * v2;
    for (int o = 32; o > 0; o >>= 1) { s1 += __shfl_down(s1, o); s2 += __shfl_down(s2, o); }
    __shared__ float ws1[4], ws2[4];
    int wid = threadIdx.x >> 6, lane = threadIdx.x & 63;
    if (lane == 0) { ws1[wid] = s1; ws2[wid] = s2; }
    __syncthreads();
    s1 = ws1[0] + ws1[1] + ws1[2] + ws1[3];
    s2 = ws2[0] + ws2[1] + ws2[2] + ws2[3];
    float mean = s1 * (1.f / DIM);
    float var = s2 * (1.f / DIM) - mean * mean;
    float inv = rsqrtf(var + 1e-5f);
    short* orow = out + (size_t)t * DIM;
    orow[threadIdx.x]       = f2bf((v0 - mean) * inv * gw[threadIdx.x]       + gb[threadIdx.x]);
    orow[threadIdx.x + 256] = f2bf((v1 - mean) * inv * gw[threadIdx.x + 256] + gb[threadIdx.x + 256]);
    orow[threadIdx.x + 512] = f2bf((v2 - mean) * inv * gw[threadIdx.x + 512] + gb[threadIdx.x + 512]);
}

// ---------------- GEMM: C[M,N] = A[M,K] (bf16) @ BT[N,K]^T (bf16) -----------
enum { EPI_QKV = 0, EPI_PROJ = 1, EPI_GELU = 2, EPI_MLP2 = 3 };
#define BM 128
#define BN 128
#define BK 32

template<int EPI>
__global__ __launch_bounds__(256) void gemm_kernel(
    const short* __restrict__ A, const short* __restrict__ BT,
    const float* __restrict__ bias, int K, int N,
    short* __restrict__ out_q, short* __restrict__ out_k, short* __restrict__ out_vt,
    const float* __restrict__ x_in, float* __restrict__ out_f, short* __restrict__ out_b) {
    __shared__ short As[BM * BK];
    __shared__ short Bs[BN * BK];
    int tile_m = blockIdx.x, tile_n = blockIdx.y;
    int tid = threadIdx.x;
    int wid = tid >> 6, lane = tid & 63, lr = lane & 15, lg = lane >> 4;
    int wr = wid >> 1, wc = wid & 1;
    f32x4 acc[4][4] = {};
    const short* Arow = A + (size_t)(tile_m * BM) * K;
    const short* Brow = BT + (size_t)(tile_n * BN) * K;
    for (int k0 = 0; k0 < K; k0 += BK) {
        for (int i = 0; i < 2; i++) {
            int ch = tid + i * 256;
            int row = ch >> 2, cb = (ch & 3) * 8;
            *(s16x8*)&As[row * BK + cb] = *(const s16x8*)&Arow[(size_t)row * K + k0 + cb];
            *(s16x8*)&Bs[row * BK + cb] = *(const s16x8*)&Brow[(size_t)row * K + k0 + cb];
        }
        __syncthreads();
        s16x8 af[4], bfr[4];
        for (int m = 0; m < 4; m++) af[m]  = *(const s16x8*)&As[(wr * 64 + m * 16 + lr) * BK + lg * 8];
        for (int n = 0; n < 4; n++) bfr[n] = *(const s16x8*)&Bs[(wc * 64 + n * 16 + lr) * BK + lg * 8];
        for (int m = 0; m < 4; m++)
            for (int n = 0; n < 4; n++)
                acc[m][n] = __builtin_amdgcn_mfma_f32_16x16x32_bf16(af[m], bfr[n], acc[m][n], 0, 0, 0);
        __syncthreads();
    }
    for (int m = 0; m < 4; m++)
        for (int n = 0; n < 4; n++)
            for (int r = 0; r < 4; r++) {
                int row = tile_m * BM + wr * 64 + m * 16 + lg * 4 + r;
                int col = tile_n * BN + wc * 64 + n * 16 + lr;
                float v = acc[m][n][r] + bias[col];
                if (EPI == EPI_QKV) {
                    int p = col / DIM, rem = col % DIM;
                    int h = rem >> 6, d = rem & 63;
                    int w = row >> 9, ntok = row & 511;
                    int wh = w * HEADS + h;
                    short bv = f2bf(v);
                    if (p == 0)      out_q[((size_t)wh * 512 + ntok) * 64 + d] = bv;
                    else if (p == 1) out_k[((size_t)wh * 512 + ntok) * 64 + d] = bv;
                    else             out_vt[((size_t)wh * 64 + d) * 512 + ntok] = bv;
                } else if (EPI == EPI_PROJ) {
                    int nr = nat_row(row);
                    out_f[(size_t)nr * DIM + col] = v + x_in[(size_t)nr * DIM + col];
                } else if (EPI == EPI_GELU) {
                    float g = 0.5f * v * (1.f + erff(v * 0.70710678118f));
                    out_b[(size_t)row * (size_t)N + col] = f2bf(g);
                } else { // EPI_MLP2
                    out_f[(size_t)row * DIM + col] += v;
                }
            }
}

// ---------------- attention: per (window*head, q-tile of 64) ----------------
__global__ __launch_bounds__(256) void attn_kernel(
    const short* __restrict__ q, const short* __restrict__ k, const short* __restrict__ vt,
    const float* __restrict__ rpd, const float* __restrict__ rph, const float* __restrict__ rpw,
    short* __restrict__ out) {
    __shared__ float bd[64][8], bh[64][8], bw[64][8];
    __shared__ short Ps[4][16 * 64];
    int qt = blockIdx.x;   // 0..7
    int wh = blockIdx.y;   // 0..191
    int win = wh / HEADS, h = wh % HEADS;
    int qbase = qt * 64;
    const short* qp = q + (size_t)wh * 512 * 64;
    const short* kp = k + (size_t)wh * 512 * 64;
    const short* vp = vt + (size_t)wh * 64 * 512;
    // decomposed rel-pos bias tables for this block's 64 q rows
    for (int i = threadIdx.x; i < 64 * 24; i += 256) {
        int qr = i / 24, e = i % 24;
        int tb = e >> 3, kidx = e & 7;
        int qtok = qbase + qr;
        int qc = (tb == 0) ? (qtok >> 6) : (tb == 1) ? ((qtok >> 3) & 7) : (qtok & 7);
        const float* R = ((tb == 0) ? rpd : (tb == 1) ? rph : rpw) + (size_t)(qc - kidx + 7) * 64;
        const short* qv = qp + (size_t)qtok * 64;
        float s = 0.f;
        for (int c2 = 0; c2 < 64; c2++) s += bf2f(qv[c2]) * R[c2];
        if (tb == 0) bd[qr][kidx] = s; else if (tb == 1) bh[qr][kidx] = s; else bw[qr][kidx] = s;
    }
    __syncthreads();
    int wid = threadIdx.x >> 6, lane = threadIdx.x & 63, lr = lane & 15, lg = lane >> 4;
    s16x8 aq[2];
    int qrow = qbase + wid * 16 + lr;
    aq[0] = *(const s16x8*)&qp[(size_t)qrow * 64 + lg * 8];
    aq[1] = *(const s16x8*)&qp[(size_t)qrow * 64 + 32 + lg * 8];
    float m_run[4], l_run[4];
    f32x4 accO[4] = {};
    for (int r = 0; r < 4; r++) { m_run[r] = -1e30f; l_run[r] = 0.f; }
    int qr0 = wid * 16 + lg * 4;
    for (int kt = 0; kt < 8; kt++) {
        f32x4 sa[4] = {};
        for (int kn = 0; kn < 4; kn++) {
            int krow = kt * 64 + kn * 16 + lr;
            s16x8 bk0 = *(const s16x8*)&kp[(size_t)krow * 64 + lg * 8];
            s16x8 bk1 = *(const s16x8*)&kp[(size_t)krow * 64 + 32 + lg * 8];
            sa[kn] = __builtin_amdgcn_mfma_f32_16x16x32_bf16(aq[0], bk0, sa[kn], 0, 0, 0);
            sa[kn] = __builtin_amdgcn_mfma_f32_16x16x32_bf16(aq[1], bk1, sa[kn], 0, 0, 0);
        }
        float sv[4][4], mx[4];
        for (int r = 0; r < 4; r++) mx[r] = -1e30f;
        for (int kn = 0; kn < 4; kn++) {
            int klocal = kn * 16 + lr;
            int kh_ = klocal >> 3, kw_ = klocal & 7;
            for (int r = 0; r < 4; r++) {
                float vv = sa[kn][r] * 0.125f + bd[qr0 + r][kt] + bh[qr0 + r][kh_] + bw[qr0 + r][kw_];
                sv[kn][r] = vv;
                mx[r] = fmaxf(mx[r], vv);
            }
        }
        for (int r = 0; r < 4; r++)
            for (int o = 1; o < 16; o <<= 1) mx[r] = fmaxf(mx[r], __shfl_xor(mx[r], o));
        float corr[4], tsum[4];
        for (int r = 0; r < 4; r++) {
            float nm = fmaxf(m_run[r], mx[r]);
            corr[r] = __expf(m_run[r] - nm);
            m_run[r] = nm;
            tsum[r] = 0.f;
        }
        float ps[4][4];
        for (int kn = 0; kn < 4; kn++)
            for (int r = 0; r < 4; r++) {
                float p = __expf(sv[kn][r] - m_run[r]);
                ps[kn][r] = p; tsum[r] += p;
            }
        for (int r = 0; r < 4; r++) {
            for (int o = 1; o < 16; o <<= 1) tsum[r] += __shfl_xor(tsum[r], o);
            l_run[r] = l_run[r] * corr[r] + tsum[r];
        }
        for (int n = 0; n < 4; n++)
            for (int r = 0; r < 4; r++) accO[n][r] *= corr[r];
        for (int kn = 0; kn < 4; kn++)
            for (int r = 0; r < 4; r++)
                Ps[wid][(lg * 4 + r) * 64 + kn * 16 + lr] = f2bf(ps[kn][r]);
        for (int s2 = 0; s2 < 2; s2++) {
            s16x8 ap = *(const s16x8*)&Ps[wid][lr * 64 + s2 * 32 + lg * 8];
            for (int n = 0; n < 4; n++) {
                s16x8 bv = *(const s16x8*)&vp[(size_t)(n * 16 + lr) * 512 + kt * 64 + s2 * 32 + lg * 8];
                accO[n] = __builtin_amdgcn_mfma_f32_16x16x32_bf16(ap, bv, accO[n], 0, 0, 0);
            }
        }
    }
    int tok = win * 512 + qbase + wid * 16 + lg * 4;
    for (int n = 0; n < 4; n++)
        for (int r = 0; r < 4; r++) {
            float o = accO[n][r] / l_run[r];
            out[(size_t)(tok + r) * DIM + h * 64 + n * 16 + lr] = f2bf(o);
        }
}

// ---------------- launch ----------------
extern "C" void kernel_launch(void* const* d_in, const int* in_sizes, int n_in,
                              void* d_out, int out_size, void* d_ws, size_t ws_size,
                              hipStream_t stream) {
    const float* x      = (const float*)d_in[0];
    const float* w_qkv  = (const float*)d_in[1];
    const float* b_qkv  = (const float*)d_in[2];
    const float* w_proj = (const float*)d_in[3];
    const float* b_proj = (const float*)d_in[4];
    const float* rpd    = (const float*)d_in[5];
    const float* rph    = (const float*)d_in[6];
    const float* rpw    = (const float*)d_in[7];
    const float* n1w    = (const float*)d_in[8];
    const float* n1b    = (const float*)d_in[9];
    const float* n2w    = (const float*)d_in[10];
    const float* n2b    = (const float*)d_in[11];
    const float* w1     = (const float*)d_in[12];
    const float* b1     = (const float*)d_in[13];
    const float* w2     = (const float*)d_in[14];
    const float* b2     = (const float*)d_in[15];
    float* out = (float*)d_out;
    char* ws = (char*)d_ws;
    size_t off = 0;
    auto alloc = [&](size_t bytes) { void* p = ws + off; off += (bytes + 255) & ~255ULL; return p; };
    short* wqkvT  = (short*)alloc((size_t)2304 * 768 * 2);
    short* wprojT = (short*)alloc((size_t)768 * 768 * 2);
    short* w1T    = (short*)alloc((size_t)3072 * 768 * 2);
    short* w2T    = (short*)alloc((size_t)768 * 3072 * 2);
    short* xn1    = (short*)alloc((size_t)8192 * 768 * 2);   // reused as attn-out
    short* qb     = (short*)alloc((size_t)192 * 512 * 64 * 2); // reused as xn2
    short* kb     = (short*)alloc((size_t)192 * 512 * 64 * 2);
    short* vtb    = (short*)alloc((size_t)192 * 512 * 64 * 2);
    short* hid    = (short*)alloc((size_t)8192 * 3072 * 2);
    short* attnout = xn1;
    short* xn2 = qb;

    transpose_cvt<<<dim3(2304 / 32, 768 / 32), 256, 0, stream>>>(w_qkv, wqkvT, 768, 2304);
    transpose_cvt<<<dim3(768 / 32, 768 / 32), 256, 0, stream>>>(w_proj, wprojT, 768, 768);
    transpose_cvt<<<dim3(3072 / 32, 768 / 32), 256, 0, stream>>>(w1, w1T, 768, 3072);
    transpose_cvt<<<dim3(768 / 32, 3072 / 32), 256, 0, stream>>>(w2, w2T, 3072, 768);

    ln_kernel<1><<<8192, 256, 0, stream>>>(x, n1w, n1b, xn1);
    gemm_kernel<EPI_QKV><<<dim3(64, 18), 256, 0, stream>>>(
        xn1, wqkvT, b_qkv, 768, 2304, qb, kb, vtb, nullptr, nullptr, nullptr);
    attn_kernel<<<dim3(8, 192), 256, 0, stream>>>(qb, kb, vtb, rpd, rph, rpw, attnout);
    gemm_kernel<EPI_PROJ><<<dim3(64, 6), 256, 0, stream>>>(
        attnout, wprojT, b_proj, 768, 768, nullptr, nullptr, nullptr, x, out, nullptr);
    ln_kernel<0><<<8192, 256, 0, stream>>>(out, n2w, n2b, xn2);
    gemm_kernel<EPI_GELU><<<dim3(64, 24), 256, 0, stream>>>(
        xn2, w1T, b1, 768, 3072, nullptr, nullptr, nullptr, nullptr, nullptr, hid);
    gemm_kernel<EPI_MLP2><<<dim3(64, 6), 256, 0, stream>>>(
        hid, w2T, b2, 3072, 768, nullptr, nullptr, nullptr, nullptr, out, nullptr);
}

// Round 2
// 1144.328 us; speedup vs baseline: 1.0158x; 1.0158x over previous
//
#include <hip/hip_runtime.h>
#include <hip/hip_bf16.h>
#include <math.h>

typedef short s16x8 __attribute__((ext_vector_type(8)));
typedef float f32x4 __attribute__((ext_vector_type(4)));

#define DIM 768
#define HEADS 12

static __device__ __forceinline__ short f2bf(float x) {
    union { float f; unsigned u; } v; v.f = x;
    unsigned r = (v.u + 0x7FFF + ((v.u >> 16) & 1)) >> 16;
    return (short)r;
}
static __device__ __forceinline__ float bf2f(short x) {
    union { unsigned u; float f; } v;
    v.u = ((unsigned)(unsigned short)x) << 16;
    return v.f;
}

// async global->LDS, 16B per lane, wave-uniform LDS base + lane*16
#define GLDS16(g, l) __builtin_amdgcn_global_load_lds( \
    (__attribute__((address_space(1))) void*)(g), \
    (__attribute__((address_space(3))) void*)(l), 16, 0, 0)

// partitioned token t (win*512+n) -> natural token index in [0, 8192)
static __device__ __forceinline__ int nat_row(int t) {
    int w = t >> 9, n = t & 511;
    int b = w >> 3, dO = (w >> 2) & 1, hO = (w >> 1) & 1, wO = w & 1;
    int di = n >> 6, hi = (n >> 3) & 7, wi = n & 7;
    int Dd = dO * 8 + di, Hh = hO * 8 + hi, Ww = wO * 8 + wi;
    return ((b * 16 + Dd) * 16 + Hh) * 16 + Ww;
}

// ---------------- weight transpose + fp32->bf16 ----------------
__global__ __launch_bounds__(256) void transpose_cvt(
    const float* __restrict__ in, short* __restrict__ out, int K, int N) {
    __shared__ float tile[32][33];
    int n0 = blockIdx.x * 32, k0 = blockIdx.y * 32;
    int tx = threadIdx.x & 31, ty = threadIdx.x >> 5;
    for (int j = 0; j < 4; j++) {
        int r = ty + j * 8;
        tile[r][tx] = in[(size_t)(k0 + r) * N + n0 + tx];
    }
    __syncthreads();
    for (int j = 0; j < 4; j++) {
        int r = ty + j * 8;
        out[(size_t)(n0 + r) * K + k0 + tx] = f2bf(tile[tx][r]);
    }
}

// ---------------- layernorm (PART=1: window-partition remap of input row) ----
template<int PART>
__global__ __launch_bounds__(256) void ln_kernel(
    const float* __restrict__ x, const float* __restrict__ gw,
    const float* __restrict__ gb, short* __restrict__ out) {
    int t = blockIdx.x;
    int row = PART ? nat_row(t) : t;
    const float* xr = x + (size_t)row * DIM;
    float v0 = xr[threadIdx.x], v1 = xr[threadIdx.x + 256], v2 = xr[threadIdx.x + 512];
    float s1 = v0 + v1 + v2;
    float s2 = v0 * v0 + v1 * v1 + v2 * v2;
    for (int o = 32; o > 0; o >>= 1) { s1 += __shfl_down(s1, o); s2 += __shfl_down(s2, o); }
    __shared__ float ws1[4], ws2[4];
    int wid = threadIdx.x >> 6, lane = threadIdx.x & 63;
    if (lane == 0) { ws1[wid] = s1; ws2[wid] = s2; }
    __syncthreads();
    s1 = ws1[0] + ws1[1] + ws1[2] + ws1[3];
    s2 = ws2[0] + ws2[1] + ws2[2] + ws2[3];
    float mean = s1 * (1.f / DIM);
    float var = s2 * (1.f / DIM) - mean * mean;
    float inv = rsqrtf(var + 1e-5f);
    short* orow = out + (size_t)t * DIM;
    orow[threadIdx.x]       = f2bf((v0 - mean) * inv * gw[threadIdx.x]       + gb[threadIdx.x]);
    orow[threadIdx.x + 256] = f2bf((v1 - mean) * inv * gw[threadIdx.x + 256] + gb[threadIdx.x + 256]);
    orow[threadIdx.x + 512] = f2bf((v2 - mean) * inv * gw[threadIdx.x + 512] + gb[threadIdx.x + 512]);
}

// ---------------- GEMM: C[M,N] = A[M,K] (bf16) @ BT[N,K]^T (bf16) -----------
// grid: (N/128, M/128); blockIdx.x = tile_n (consecutive blocks share A-panel,
// weights stay L2-resident). global_load_lds staging with source-side quad
// swizzle so frag ds_read_b128 is conflict-free.
enum { EPI_C = 0, EPI_PROJ = 1, EPI_GELU = 2, EPI_MLP2 = 3 };

template<int EPI>
__global__ __launch_bounds__(256) void gemm_kernel(
    const short* __restrict__ A, const short* __restrict__ BT,
    const float* __restrict__ bias, int K, int N,
    const float* __restrict__ x_in, float* __restrict__ out_f,
    short* __restrict__ out_b) {
    __shared__ short As[128 * 32];
    __shared__ short Bs[128 * 32];
    int tile_n = blockIdx.x, tile_m = blockIdx.y;
    int tid = threadIdx.x;
    int wid = tid >> 6, lane = tid & 63, lr = lane & 15, lg = lane >> 4;
    int wr = wid >> 1, wc = wid & 1;
    f32x4 acc[4][4] = {};
    const short* Arow = A + (size_t)(tile_m * 128) * K;
    const short* Brow = BT + (size_t)(tile_n * 128) * K;
    // staging geometry: chunk c (0..7) of each array = rows c*16..c*16+15,
    // lane l -> row c*16+(l>>2), quad (l&3); source quad swizzled by (row>>1)&3
    int c0 = wid * 2, c1 = wid * 2 + 1;
    int rl0 = c0 * 16 + (lane >> 2), rl1 = c1 * 16 + (lane >> 2);
    int sq0 = ((lane & 3) ^ ((rl0 >> 1) & 3)) * 8;
    int sq1 = ((lane & 3) ^ ((rl1 >> 1) & 3)) * 8;
    const short* gA0 = Arow + (size_t)rl0 * K + sq0;
    const short* gA1 = Arow + (size_t)rl1 * K + sq1;
    const short* gB0 = Brow + (size_t)rl0 * K + sq0;
    const short* gB1 = Brow + (size_t)rl1 * K + sq1;
    for (int k0 = 0; k0 < K; k0 += 32) {
        GLDS16(gA0 + k0, &As[c0 * 512]);
        GLDS16(gA1 + k0, &As[c1 * 512]);
        GLDS16(gB0 + k0, &Bs[c0 * 512]);
        GLDS16(gB1 + k0, &Bs[c1 * 512]);
        __syncthreads();
        s16x8 af[4], bfr[4];
        for (int m = 0; m < 4; m++) {
            int row = wr * 64 + m * 16 + lr;
            af[m] = *(const s16x8*)&As[row * 32 + ((lg ^ ((row >> 1) & 3)) << 3)];
        }
        for (int n = 0; n < 4; n++) {
            int row = wc * 64 + n * 16 + lr;
            bfr[n] = *(const s16x8*)&Bs[row * 32 + ((lg ^ ((row >> 1) & 3)) << 3)];
        }
        for (int m = 0; m < 4; m++)
            for (int n = 0; n < 4; n++)
                acc[m][n] = __builtin_amdgcn_mfma_f32_16x16x32_bf16(af[m], bfr[n], acc[m][n], 0, 0, 0);
        __syncthreads();
    }
    for (int m = 0; m < 4; m++)
        for (int n = 0; n < 4; n++)
            for (int r = 0; r < 4; r++) {
                int row = tile_m * 128 + wr * 64 + m * 16 + lg * 4 + r;
                int col = tile_n * 128 + wc * 64 + n * 16 + lr;
                float v = acc[m][n][r] + bias[col];
                if (EPI == EPI_C) {
                    out_b[(size_t)row * N + col] = f2bf(v);
                } else if (EPI == EPI_PROJ) {
                    int nr = nat_row(row);
                    out_f[(size_t)nr * DIM + col] = v + x_in[(size_t)nr * DIM + col];
                } else if (EPI == EPI_GELU) {
                    float g = 0.5f * v * (1.f + erff(v * 0.70710678118f));
                    out_b[(size_t)row * (size_t)N + col] = f2bf(g);
                } else { // EPI_MLP2
                    out_f[(size_t)row * DIM + col] += v;
                }
            }
}

// ---------------- V repack: qkv[t, 1536+h*64+d] -> vt[wh][d][tok] ----------
__global__ __launch_bounds__(256) void repack_vt(
    const short* __restrict__ qkv, short* __restrict__ vt) {
    __shared__ short tile[64][72];   // 144B row stride, 16B aligned
    int ntb = blockIdx.x, wh = blockIdx.y;
    int win = wh / HEADS, h = wh % HEADS;
    const short* vbase = qkv + (size_t)(win * 512 + ntb * 64) * 2304 + 1536 + h * 64;
    int tid = threadIdx.x;
    for (int p = 0; p < 2; p++) {
        int idx = tid + p * 256;
        int tok = idx >> 3, vc = idx & 7;
        s16x8 v = *(const s16x8*)&vbase[(size_t)tok * 2304 + vc * 8];
        for (int j = 0; j < 8; j++) tile[vc * 8 + j][tok] = v[j];
    }
    __syncthreads();
    for (int p = 0; p < 2; p++) {
        int idx = tid + p * 256;
        int d = idx >> 3, vc = idx & 7;
        s16x8 o = *(const s16x8*)&tile[d][vc * 8];
        *(s16x8*)&vt[((size_t)wh * 64 + d) * 512 + ntb * 64 + vc * 8] = o;
    }
}

// ---------------- attention: per (q-tile of 64, window*head) ----------------
__global__ __launch_bounds__(256) void attn_kernel(
    const short* __restrict__ qkv, const short* __restrict__ vt,
    const float* __restrict__ rpd, const float* __restrict__ rph,
    const float* __restrict__ rpw, short* __restrict__ out) {
    __shared__ float bd[64][8], bh[64][8], bw[64][8];
    __shared__ short Ps[4][16 * 64];
    int qt = blockIdx.x;   // 0..7
    int wh = blockIdx.y;   // 0..191
    int win = wh / HEADS, h = wh % HEADS;
    int qbase = qt * 64;
    const short* qp = qkv + (size_t)(win * 512) * 2304 + h * 64;         // row stride 2304
    const short* kp = qp + 768;
    const short* vp = vt + (size_t)wh * 64 * 512;
    // decomposed rel-pos bias tables for this block's 64 q rows
    for (int i = threadIdx.x; i < 64 * 24; i += 256) {
        int qr = i / 24, e = i % 24;
        int tb = e >> 3, kidx = e & 7;
        int qtok = qbase + qr;
        int qc = (tb == 0) ? (qtok >> 6) : (tb == 1) ? ((qtok >> 3) & 7) : (qtok & 7);
        const float* R = ((tb == 0) ? rpd : (tb == 1) ? rph : rpw) + (size_t)(qc - kidx + 7) * 64;
        const short* qv = qp + (size_t)qtok * 2304;
        float s = 0.f;
        for (int c8 = 0; c8 < 8; c8++) {
            s16x8 q8 = *(const s16x8*)&qv[c8 * 8];
            for (int j = 0; j < 8; j++) s += bf2f(q8[j]) * R[c8 * 8 + j];
        }
        if (tb == 0) bd[qr][kidx] = s; else if (tb == 1) bh[qr][kidx] = s; else bw[qr][kidx] = s;
    }
    __syncthreads();
    int wid = threadIdx.x >> 6, lane = threadIdx.x & 63, lr = lane & 15, lg = lane >> 4;
    s16x8 aq[2];
    {
        size_t qoff = (size_t)(qbase + wid * 16 + lr) * 2304;
        aq[0] = *(const s16x8*)&qp[qoff + lg * 8];
        aq[1] = *(const s16x8*)&qp[qoff + 32 + lg * 8];
    }
    float m_run[4], l_run[4];
    f32x4 accO[4] = {};
    for (int r = 0; r < 4; r++) { m_run[r] = -1e30f; l_run[r] = 0.f; }
    int qr0 = wid * 16 + lg * 4;
    for (int kt = 0; kt < 8; kt++) {
        f32x4 sa[4] = {};
        for (int kn = 0; kn < 4; kn++) {
            size_t koff = (size_t)(kt * 64 + kn * 16 + lr) * 2304;
            s16x8 bk0 = *(const s16x8*)&kp[koff + lg * 8];
            s16x8 bk1 = *(const s16x8*)&kp[koff + 32 + lg * 8];
            sa[kn] = __builtin_amdgcn_mfma_f32_16x16x32_bf16(aq[0], bk0, sa[kn], 0, 0, 0);
            sa[kn] = __builtin_amdgcn_mfma_f32_16x16x32_bf16(aq[1], bk1, sa[kn], 0, 0, 0);
        }
        float sv[4][4], mx[4];
        for (int r = 0; r < 4; r++) mx[r] = -1e30f;
        for (int kn = 0; kn < 4; kn++) {
            int klocal = kn * 16 + lr;
            int kh_ = klocal >> 3, kw_ = klocal & 7;
            for (int r = 0; r < 4; r++) {
                float vv = sa[kn][r] * 0.125f + bd[qr0 + r][kt] + bh[qr0 + r][kh_] + bw[qr0 + r][kw_];
                sv[kn][r] = vv;
                mx[r] = fmaxf(mx[r], vv);
            }
        }
        for (int r = 0; r < 4; r++)
            for (int o = 1; o < 16; o <<= 1) mx[r] = fmaxf(mx[r], __shfl_xor(mx[r], o));
        float corr[4], tsum[4];
        for (int r = 0; r < 4; r++) {
            float nm = fmaxf(m_run[r], mx[r]);
            corr[r] = __expf(m_run[r] - nm);
            m_run[r] = nm;
            tsum[r] = 0.f;
        }
        float ps[4][4];
        for (int kn = 0; kn < 4; kn++)
            for (int r = 0; r < 4; r++) {
                float p = __expf(sv[kn][r] - m_run[r]);
                ps[kn][r] = p; tsum[r] += p;
            }
        for (int r = 0; r < 4; r++) {
            for (int o = 1; o < 16; o <<= 1) tsum[r] += __shfl_xor(tsum[r], o);
            l_run[r] = l_run[r] * corr[r] + tsum[r];
        }
        for (int n = 0; n < 4; n++)
            for (int r = 0; r < 4; r++) accO[n][r] *= corr[r];
        for (int kn = 0; kn < 4; kn++)
            for (int r = 0; r < 4; r++)
                Ps[wid][(lg * 4 + r) * 64 + kn * 16 + lr] = f2bf(ps[kn][r]);
        for (int s2 = 0; s2 < 2; s2++) {
            s16x8 ap = *(const s16x8*)&Ps[wid][lr * 64 + s2 * 32 + lg * 8];
            for (int n = 0; n < 4; n++) {
                s16x8 bv = *(const s16x8*)&vp[(size_t)(n * 16 + lr) * 512 + kt * 64 + s2 * 32 + lg * 8];
                accO[n] = __builtin_amdgcn_mfma_f32_16x16x32_bf16(ap, bv, accO[n], 0, 0, 0);
            }
        }
    }
    int tok = win * 512 + qbase + wid * 16 + lg * 4;
    for (int n = 0; n < 4; n++)
        for (int r = 0; r < 4; r++) {
            float o = accO[n][r] / l_run[r];
            out[(size_t)(tok + r) * DIM + h * 64 + n * 16 + lr] = f2bf(o);
        }
}

// ---------------- launch ----------------
extern "C" void kernel_launch(void* const* d_in, const int* in_sizes, int n_in,
                              void* d_out, int out_size, void* d_ws, size_t ws_size,
                              hipStream_t stream) {
    const float* x      = (const float*)d_in[0];
    const float* w_qkv  = (const float*)d_in[1];
    const float* b_qkv  = (const float*)d_in[2];
    const float* w_proj = (const float*)d_in[3];
    const float* b_proj = (const float*)d_in[4];
    const float* rpd    = (const float*)d_in[5];
    const float* rph    = (const float*)d_in[6];
    const float* rpw    = (const float*)d_in[7];
    const float* n1w    = (const float*)d_in[8];
    const float* n1b    = (const float*)d_in[9];
    const float* n2w    = (const float*)d_in[10];
    const float* n2b    = (const float*)d_in[11];
    const float* w1     = (const float*)d_in[12];
    const float* b1     = (const float*)d_in[13];
    const float* w2     = (const float*)d_in[14];
    const float* b2     = (const float*)d_in[15];
    float* out = (float*)d_out;
    char* ws = (char*)d_ws;
    size_t off = 0;
    auto alloc = [&](size_t bytes) { void* p = ws + off; off += (bytes + 255) & ~255ULL; return p; };
    short* wqkvT  = (short*)alloc((size_t)2304 * 768 * 2);
    short* wprojT = (short*)alloc((size_t)768 * 768 * 2);
    short* w1T    = (short*)alloc((size_t)3072 * 768 * 2);
    short* w2T    = (short*)alloc((size_t)768 * 3072 * 2);
    short* xn1    = (short*)alloc((size_t)8192 * 768 * 2);   // reused as attn-out
    short* qkvC   = (short*)alloc((size_t)8192 * 2304 * 2);
    short* vtb    = (short*)alloc((size_t)192 * 64 * 512 * 2);
    short* xn2    = (short*)alloc((size_t)8192 * 768 * 2);
    short* hid    = (short*)alloc((size_t)8192 * 3072 * 2);
    short* attnout = xn1;

    transpose_cvt<<<dim3(2304 / 32, 768 / 32), 256, 0, stream>>>(w_qkv, wqkvT, 768, 2304);
    transpose_cvt<<<dim3(768 / 32, 768 / 32), 256, 0, stream>>>(w_proj, wprojT, 768, 768);
    transpose_cvt<<<dim3(3072 / 32, 768 / 32), 256, 0, stream>>>(w1, w1T, 768, 3072);
    transpose_cvt<<<dim3(768 / 32, 3072 / 32), 256, 0, stream>>>(w2, w2T, 3072, 768);

    ln_kernel<1><<<8192, 256, 0, stream>>>(x, n1w, n1b, xn1);
    gemm_kernel<EPI_C><<<dim3(18, 64), 256, 0, stream>>>(
        xn1, wqkvT, b_qkv, 768, 2304, nullptr, nullptr, qkvC);
    repack_vt<<<dim3(8, 192), 256, 0, stream>>>(qkvC, vtb);
    attn_kernel<<<dim3(8, 192), 256, 0, stream>>>(qkvC, vtb, rpd, rph, rpw, attnout);
    gemm_kernel<EPI_PROJ><<<dim3(6, 64), 256, 0, stream>>>(
        attnout, wprojT, b_proj, 768, 768, x, out, nullptr);
    ln_kernel<0><<<8192, 256, 0, stream>>>(out, n2w, n2b, xn2);
    gemm_kernel<EPI_GELU><<<dim3(24, 64), 256, 0, stream>>>(
        xn2, w1T, b1, 768, 3072, nullptr, nullptr, hid);
    gemm_kernel<EPI_MLP2><<<dim3(6, 64), 256, 0, stream>>>(
        hid, w2T, b2, 3072, 768, nullptr, out, nullptr);
}

// Round 3
// 460.194 us; speedup vs baseline: 2.5260x; 2.4866x over previous
//
#include <hip/hip_runtime.h>
#include <hip/hip_bf16.h>
#include <math.h>

typedef short s16x8 __attribute__((ext_vector_type(8)));
typedef float f32x4 __attribute__((ext_vector_type(4)));

#define DIM 768
#define HEADS 12

static __device__ __forceinline__ short f2bf(float x) {
    union { float f; unsigned u; } v; v.f = x;
    unsigned r = (v.u + 0x7FFF + ((v.u >> 16) & 1)) >> 16;
    return (short)r;
}
static __device__ __forceinline__ float bf2f(short x) {
    union { unsigned u; float f; } v;
    v.u = ((unsigned)(unsigned short)x) << 16;
    return v.f;
}

// async global->LDS, 16B per lane, wave-uniform LDS base + lane*16
#define GLDS16(g, l) __builtin_amdgcn_global_load_lds( \
    (__attribute__((address_space(1))) void*)(g), \
    (__attribute__((address_space(3))) void*)(l), 16, 0, 0)

// partitioned token t (win*512+n) -> natural token index in [0, 8192)
static __device__ __forceinline__ int nat_row(int t) {
    int w = t >> 9, n = t & 511;
    int b = w >> 3, dO = (w >> 2) & 1, hO = (w >> 1) & 1, wO = w & 1;
    int di = n >> 6, hi = (n >> 3) & 7, wi = n & 7;
    int Dd = dO * 8 + di, Hh = hO * 8 + hi, Ww = wO * 8 + wi;
    return ((b * 16 + Dd) * 16 + Hh) * 16 + Ww;
}

// ---------------- weight transpose + fp32->bf16 ----------------
__global__ __launch_bounds__(256) void transpose_cvt(
    const float* __restrict__ in, short* __restrict__ out, int K, int N) {
    __shared__ float tile[32][33];
    int n0 = blockIdx.x * 32, k0 = blockIdx.y * 32;
    int tx = threadIdx.x & 31, ty = threadIdx.x >> 5;
#pragma unroll
    for (int j = 0; j < 4; j++) {
        int r = ty + j * 8;
        tile[r][tx] = in[(size_t)(k0 + r) * N + n0 + tx];
    }
    __syncthreads();
#pragma unroll
    for (int j = 0; j < 4; j++) {
        int r = ty + j * 8;
        out[(size_t)(n0 + r) * K + k0 + tx] = f2bf(tile[tx][r]);
    }
}

// ---------------- layernorm (PART=1: window-partition remap of input row) ----
template<int PART>
__global__ __launch_bounds__(256) void ln_kernel(
    const float* __restrict__ x, const float* __restrict__ gw,
    const float* __restrict__ gb, short* __restrict__ out) {
    int t = blockIdx.x;
    int row = PART ? nat_row(t) : t;
    const float* xr = x + (size_t)row * DIM;
    float v0 = xr[threadIdx.x], v1 = xr[threadIdx.x + 256], v2 = xr[threadIdx.x + 512];
    float s1 = v0 + v1 + v2;
    float s2 = v0 * v0 + v1 * v1 + v2 * v2;
#pragma unroll
    for (int o = 32; o > 0; o >>= 1) { s1 += __shfl_down(s1, o); s2 += __shfl_down(s2, o); }
    __shared__ float ws1[4], ws2[4];
    int wid = threadIdx.x >> 6, lane = threadIdx.x & 63;
    if (lane == 0) { ws1[wid] = s1; ws2[wid] = s2; }
    __syncthreads();
    s1 = ws1[0] + ws1[1] + ws1[2] + ws1[3];
    s2 = ws2[0] + ws2[1] + ws2[2] + ws2[3];
    float mean = s1 * (1.f / DIM);
    float var = s2 * (1.f / DIM) - mean * mean;
    float inv = rsqrtf(var + 1e-5f);
    short* orow = out + (size_t)t * DIM;
    orow[threadIdx.x]       = f2bf((v0 - mean) * inv * gw[threadIdx.x]       + gb[threadIdx.x]);
    orow[threadIdx.x + 256] = f2bf((v1 - mean) * inv * gw[threadIdx.x + 256] + gb[threadIdx.x + 256]);
    orow[threadIdx.x + 512] = f2bf((v2 - mean) * inv * gw[threadIdx.x + 512] + gb[threadIdx.x + 512]);
}

// ---------------- GEMM: C[M,N] = A[M,K] (bf16) @ BT[N,K]^T (bf16) -----------
// grid: (N/128, M/128). Compile-time K,N; all constant loops force-unrolled
// so frag/acc arrays are SROA-promoted to registers (round-2 showed scratch
// spill: VGPR_Count=28, 3.9 GB/dispatch HBM traffic).
enum { EPI_C = 0, EPI_PROJ = 1, EPI_GELU = 2, EPI_MLP2 = 3 };

template<int EPI, int K, int N>
__global__ __launch_bounds__(256) void gemm_kernel(
    const short* __restrict__ A, const short* __restrict__ BT,
    const float* __restrict__ bias,
    const float* __restrict__ x_in, float* __restrict__ out_f,
    short* __restrict__ out_b) {
    __shared__ short As[128 * 32];
    __shared__ short Bs[128 * 32];
    int tile_n = blockIdx.x, tile_m = blockIdx.y;
    int tid = threadIdx.x;
    int wid = tid >> 6, lane = tid & 63, lr = lane & 15, lg = lane >> 4;
    int wr = wid >> 1, wc = wid & 1;
    f32x4 acc[4][4] = {};
    const short* Arow = A + (size_t)(tile_m * 128) * K;
    const short* Brow = BT + (size_t)(tile_n * 128) * K;
    // staging geometry: chunk c (0..7) = rows c*16..c*16+15; lane l -> row
    // c*16+(l>>2), quad (l&3); source quad pre-swizzled by (row>>1)&3 so the
    // frag ds_read_b128 below is bank-conflict-free (verified: conflicts=0)
    int c0 = wid * 2, c1 = wid * 2 + 1;
    int rl0 = c0 * 16 + (lane >> 2), rl1 = c1 * 16 + (lane >> 2);
    int sq0 = ((lane & 3) ^ ((rl0 >> 1) & 3)) * 8;
    int sq1 = ((lane & 3) ^ ((rl1 >> 1) & 3)) * 8;
    const short* gA0 = Arow + (size_t)rl0 * K + sq0;
    const short* gA1 = Arow + (size_t)rl1 * K + sq1;
    const short* gB0 = Brow + (size_t)rl0 * K + sq0;
    const short* gB1 = Brow + (size_t)rl1 * K + sq1;
#pragma unroll 1
    for (int k0 = 0; k0 < K; k0 += 32) {
        GLDS16(gA0 + k0, &As[c0 * 512]);
        GLDS16(gA1 + k0, &As[c1 * 512]);
        GLDS16(gB0 + k0, &Bs[c0 * 512]);
        GLDS16(gB1 + k0, &Bs[c1 * 512]);
        __syncthreads();
        s16x8 af[4], bfr[4];
#pragma unroll
        for (int m = 0; m < 4; m++) {
            int row = wr * 64 + m * 16 + lr;
            af[m] = *(const s16x8*)&As[row * 32 + ((lg ^ ((row >> 1) & 3)) << 3)];
        }
#pragma unroll
        for (int n = 0; n < 4; n++) {
            int row = wc * 64 + n * 16 + lr;
            bfr[n] = *(const s16x8*)&Bs[row * 32 + ((lg ^ ((row >> 1) & 3)) << 3)];
        }
#pragma unroll
        for (int m = 0; m < 4; m++)
#pragma unroll
            for (int n = 0; n < 4; n++)
                acc[m][n] = __builtin_amdgcn_mfma_f32_16x16x32_bf16(af[m], bfr[n], acc[m][n], 0, 0, 0);
        __syncthreads();
    }
#pragma unroll
    for (int m = 0; m < 4; m++)
#pragma unroll
        for (int n = 0; n < 4; n++)
#pragma unroll
            for (int r = 0; r < 4; r++) {
                int row = tile_m * 128 + wr * 64 + m * 16 + lg * 4 + r;
                int col = tile_n * 128 + wc * 64 + n * 16 + lr;
                float v = acc[m][n][r] + bias[col];
                if (EPI == EPI_C) {
                    out_b[(size_t)row * N + col] = f2bf(v);
                } else if (EPI == EPI_PROJ) {
                    int nr = nat_row(row);
                    out_f[(size_t)nr * DIM + col] = v + x_in[(size_t)nr * DIM + col];
                } else if (EPI == EPI_GELU) {
                    float g = 0.5f * v * (1.f + erff(v * 0.70710678118f));
                    out_b[(size_t)row * (size_t)N + col] = f2bf(g);
                } else { // EPI_MLP2
                    out_f[(size_t)row * DIM + col] += v;
                }
            }
}

// ---------------- V repack: qkv[t, 1536+h*64+d] -> vt[wh][d][tok] ----------
__global__ __launch_bounds__(256) void repack_vt(
    const short* __restrict__ qkv, short* __restrict__ vt) {
    __shared__ short tile[64][72];   // 144B row stride, 16B aligned
    int ntb = blockIdx.x, wh = blockIdx.y;
    int win = wh / HEADS, h = wh % HEADS;
    const short* vbase = qkv + (size_t)(win * 512 + ntb * 64) * 2304 + 1536 + h * 64;
    int tid = threadIdx.x;
#pragma unroll
    for (int p = 0; p < 2; p++) {
        int idx = tid + p * 256;
        int tok = idx >> 3, vc = idx & 7;
        s16x8 v = *(const s16x8*)&vbase[(size_t)tok * 2304 + vc * 8];
#pragma unroll
        for (int j = 0; j < 8; j++) tile[vc * 8 + j][tok] = v[j];
    }
    __syncthreads();
#pragma unroll
    for (int p = 0; p < 2; p++) {
        int idx = tid + p * 256;
        int d = idx >> 3, vc = idx & 7;
        s16x8 o = *(const s16x8*)&tile[d][vc * 8];
        *(s16x8*)&vt[((size_t)wh * 64 + d) * 512 + ntb * 64 + vc * 8] = o;
    }
}

// ---------------- attention: per (q-tile of 64, window*head) ----------------
__global__ __launch_bounds__(256) void attn_kernel(
    const short* __restrict__ qkv, const short* __restrict__ vt,
    const float* __restrict__ rpd, const float* __restrict__ rph,
    const float* __restrict__ rpw, short* __restrict__ out) {
    __shared__ float bd[64][8], bh[64][8], bw[64][8];
    __shared__ short Ps[4][16 * 64];
    int qt = blockIdx.x;   // 0..7
    int wh = blockIdx.y;   // 0..191
    int win = wh / HEADS, h = wh % HEADS;
    int qbase = qt * 64;
    const short* qp = qkv + (size_t)(win * 512) * 2304 + h * 64;  // row stride 2304
    const short* kp = qp + 768;
    const short* vp = vt + (size_t)wh * 64 * 512;
    // decomposed rel-pos bias tables for this block's 64 q rows
    for (int i = threadIdx.x; i < 64 * 24; i += 256) {
        int qr = i / 24, e = i % 24;
        int tb = e >> 3, kidx = e & 7;
        int qtok = qbase + qr;
        int qc = (tb == 0) ? (qtok >> 6) : (tb == 1) ? ((qtok >> 3) & 7) : (qtok & 7);
        const float* R = ((tb == 0) ? rpd : (tb == 1) ? rph : rpw) + (size_t)(qc - kidx + 7) * 64;
        const short* qv = qp + (size_t)qtok * 2304;
        float s = 0.f;
#pragma unroll
        for (int c8 = 0; c8 < 8; c8++) {
            s16x8 q8 = *(const s16x8*)&qv[c8 * 8];
#pragma unroll
            for (int j = 0; j < 8; j++) s += bf2f(q8[j]) * R[c8 * 8 + j];
        }
        if (tb == 0) bd[qr][kidx] = s; else if (tb == 1) bh[qr][kidx] = s; else bw[qr][kidx] = s;
    }
    __syncthreads();
    int wid = threadIdx.x >> 6, lane = threadIdx.x & 63, lr = lane & 15, lg = lane >> 4;
    s16x8 aq[2];
    {
        size_t qoff = (size_t)(qbase + wid * 16 + lr) * 2304;
        aq[0] = *(const s16x8*)&qp[qoff + lg * 8];
        aq[1] = *(const s16x8*)&qp[qoff + 32 + lg * 8];
    }
    float m_run[4], l_run[4];
    f32x4 accO[4] = {};
#pragma unroll
    for (int r = 0; r < 4; r++) { m_run[r] = -1e30f; l_run[r] = 0.f; }
    int qr0 = wid * 16 + lg * 4;
#pragma unroll 1
    for (int kt = 0; kt < 8; kt++) {
        f32x4 sa[4] = {};
#pragma unroll
        for (int kn = 0; kn < 4; kn++) {
            size_t koff = (size_t)(kt * 64 + kn * 16 + lr) * 2304;
            s16x8 bk0 = *(const s16x8*)&kp[koff + lg * 8];
            s16x8 bk1 = *(const s16x8*)&kp[koff + 32 + lg * 8];
            sa[kn] = __builtin_amdgcn_mfma_f32_16x16x32_bf16(aq[0], bk0, sa[kn], 0, 0, 0);
            sa[kn] = __builtin_amdgcn_mfma_f32_16x16x32_bf16(aq[1], bk1, sa[kn], 0, 0, 0);
        }
        float sv[4][4], mx[4];
#pragma unroll
        for (int r = 0; r < 4; r++) mx[r] = -1e30f;
#pragma unroll
        for (int kn = 0; kn < 4; kn++) {
            int klocal = kn * 16 + lr;
            int kh_ = klocal >> 3, kw_ = klocal & 7;
#pragma unroll
            for (int r = 0; r < 4; r++) {
                float vv = sa[kn][r] * 0.125f + bd[qr0 + r][kt] + bh[qr0 + r][kh_] + bw[qr0 + r][kw_];
                sv[kn][r] = vv;
                mx[r] = fmaxf(mx[r], vv);
            }
        }
#pragma unroll
        for (int r = 0; r < 4; r++)
#pragma unroll
            for (int o = 1; o < 16; o <<= 1) mx[r] = fmaxf(mx[r], __shfl_xor(mx[r], o));
        float corr[4], tsum[4];
#pragma unroll
        for (int r = 0; r < 4; r++) {
            float nm = fmaxf(m_run[r], mx[r]);
            corr[r] = __expf(m_run[r] - nm);
            m_run[r] = nm;
            tsum[r] = 0.f;
        }
        float ps[4][4];
#pragma unroll
        for (int kn = 0; kn < 4; kn++)
#pragma unroll
            for (int r = 0; r < 4; r++) {
                float p = __expf(sv[kn][r] - m_run[r]);
                ps[kn][r] = p; tsum[r] += p;
            }
#pragma unroll
        for (int r = 0; r < 4; r++) {
#pragma unroll
            for (int o = 1; o < 16; o <<= 1) tsum[r] += __shfl_xor(tsum[r], o);
            l_run[r] = l_run[r] * corr[r] + tsum[r];
        }
#pragma unroll
        for (int n = 0; n < 4; n++)
#pragma unroll
            for (int r = 0; r < 4; r++) accO[n][r] *= corr[r];
#pragma unroll
        for (int kn = 0; kn < 4; kn++)
#pragma unroll
            for (int r = 0; r < 4; r++)
                Ps[wid][(lg * 4 + r) * 64 + kn * 16 + lr] = f2bf(ps[kn][r]);
#pragma unroll
        for (int s2 = 0; s2 < 2; s2++) {
            s16x8 ap = *(const s16x8*)&Ps[wid][lr * 64 + s2 * 32 + lg * 8];
#pragma unroll
            for (int n = 0; n < 4; n++) {
                s16x8 bv = *(const s16x8*)&vp[(size_t)(n * 16 + lr) * 512 + kt * 64 + s2 * 32 + lg * 8];
                accO[n] = __builtin_amdgcn_mfma_f32_16x16x32_bf16(ap, bv, accO[n], 0, 0, 0);
            }
        }
    }
    int tok = win * 512 + qbase + wid * 16 + lg * 4;
#pragma unroll
    for (int n = 0; n < 4; n++)
#pragma unroll
        for (int r = 0; r < 4; r++) {
            float o = accO[n][r] / l_run[r];
            out[(size_t)(tok + r) * DIM + h * 64 + n * 16 + lr] = f2bf(o);
        }
}

// ---------------- launch ----------------
extern "C" void kernel_launch(void* const* d_in, const int* in_sizes, int n_in,
                              void* d_out, int out_size, void* d_ws, size_t ws_size,
                              hipStream_t stream) {
    const float* x      = (const float*)d_in[0];
    const float* w_qkv  = (const float*)d_in[1];
    const float* b_qkv  = (const float*)d_in[2];
    const float* w_proj = (const float*)d_in[3];
    const float* b_proj = (const float*)d_in[4];
    const float* rpd    = (const float*)d_in[5];
    const float* rph    = (const float*)d_in[6];
    const float* rpw    = (const float*)d_in[7];
    const float* n1w    = (const float*)d_in[8];
    const float* n1b    = (const float*)d_in[9];
    const float* n2w    = (const float*)d_in[10];
    const float* n2b    = (const float*)d_in[11];
    const float* w1     = (const float*)d_in[12];
    const float* b1     = (const float*)d_in[13];
    const float* w2     = (const float*)d_in[14];
    const float* b2     = (const float*)d_in[15];
    float* out = (float*)d_out;
    char* ws = (char*)d_ws;
    size_t off = 0;
    auto alloc = [&](size_t bytes) { void* p = ws + off; off += (bytes + 255) & ~255ULL; return p; };
    short* wqkvT  = (short*)alloc((size_t)2304 * 768 * 2);
    short* wprojT = (short*)alloc((size_t)768 * 768 * 2);
    short* w1T    = (short*)alloc((size_t)3072 * 768 * 2);
    short* w2T    = (short*)alloc((size_t)768 * 3072 * 2);
    short* xn1    = (short*)alloc((size_t)8192 * 768 * 2);   // reused as attn-out
    short* qkvC   = (short*)alloc((size_t)8192 * 2304 * 2);
    short* vtb    = (short*)alloc((size_t)192 * 64 * 512 * 2);
    short* xn2    = (short*)alloc((size_t)8192 * 768 * 2);
    short* hid    = (short*)alloc((size_t)8192 * 3072 * 2);
    short* attnout = xn1;

    transpose_cvt<<<dim3(2304 / 32, 768 / 32), 256, 0, stream>>>(w_qkv, wqkvT, 768, 2304);
    transpose_cvt<<<dim3(768 / 32, 768 / 32), 256, 0, stream>>>(w_proj, wprojT, 768, 768);
    transpose_cvt<<<dim3(3072 / 32, 768 / 32), 256, 0, stream>>>(w1, w1T, 768, 3072);
    transpose_cvt<<<dim3(768 / 32, 3072 / 32), 256, 0, stream>>>(w2, w2T, 3072, 768);

    ln_kernel<1><<<8192, 256, 0, stream>>>(x, n1w, n1b, xn1);
    gemm_kernel<EPI_C, 768, 2304><<<dim3(18, 64), 256, 0, stream>>>(
        xn1, wqkvT, b_qkv, nullptr, nullptr, qkvC);
    repack_vt<<<dim3(8, 192), 256, 0, stream>>>(qkvC, vtb);
    attn_kernel<<<dim3(8, 192), 256, 0, stream>>>(qkvC, vtb, rpd, rph, rpw, attnout);
    gemm_kernel<EPI_PROJ, 768, 768><<<dim3(6, 64), 256, 0, stream>>>(
        attnout, wprojT, b_proj, x, out, nullptr);
    ln_kernel<0><<<8192, 256, 0, stream>>>(out, n2w, n2b, xn2);
    gemm_kernel<EPI_GELU, 768, 3072><<<dim3(24, 64), 256, 0, stream>>>(
        xn2, w1T, b1, nullptr, nullptr, hid);
    gemm_kernel<EPI_MLP2, 3072, 768><<<dim3(6, 64), 256, 0, stream>>>(
        hid, w2T, b2, nullptr, out, nullptr);
}

// Round 4
// 394.457 us; speedup vs baseline: 2.9470x; 1.1667x over previous
//
#include <hip/hip_runtime.h>
#include <hip/hip_bf16.h>
#include <math.h>

typedef short s16x8 __attribute__((ext_vector_type(8)));
typedef float f32x4 __attribute__((ext_vector_type(4)));

#define DIM 768
#define HEADS 12

static __device__ __forceinline__ short f2bf(float x) {
    union { float f; unsigned u; } v; v.f = x;
    unsigned r = (v.u + 0x7FFF + ((v.u >> 16) & 1)) >> 16;
    return (short)r;
}
static __device__ __forceinline__ float bf2f(short x) {
    union { unsigned u; float f; } v;
    v.u = ((unsigned)(unsigned short)x) << 16;
    return v.f;
}

// async global->LDS, 16B per lane, wave-uniform LDS base + lane*16
#define GLDS16(g, l) __builtin_amdgcn_global_load_lds( \
    (__attribute__((address_space(1))) void*)(g), \
    (__attribute__((address_space(3))) void*)(l), 16, 0, 0)

// partitioned token t (win*512+n) -> natural token index in [0, 8192)
static __device__ __forceinline__ int nat_row(int t) {
    int w = t >> 9, n = t & 511;
    int b = w >> 3, dO = (w >> 2) & 1, hO = (w >> 1) & 1, wO = w & 1;
    int di = n >> 6, hi = (n >> 3) & 7, wi = n & 7;
    int Dd = dO * 8 + di, Hh = hO * 8 + hi, Ww = wO * 8 + wi;
    return ((b * 16 + Dd) * 16 + Hh) * 16 + Ww;
}

// ---------------- weight transpose + fp32->bf16 ----------------
__global__ __launch_bounds__(256) void transpose_cvt(
    const float* __restrict__ in, short* __restrict__ out, int K, int N) {
    __shared__ float tile[32][33];
    int n0 = blockIdx.x * 32, k0 = blockIdx.y * 32;
    int tx = threadIdx.x & 31, ty = threadIdx.x >> 5;
#pragma unroll
    for (int j = 0; j < 4; j++) {
        int r = ty + j * 8;
        tile[r][tx] = in[(size_t)(k0 + r) * N + n0 + tx];
    }
    __syncthreads();
#pragma unroll
    for (int j = 0; j < 4; j++) {
        int r = ty + j * 8;
        out[(size_t)(n0 + r) * K + k0 + tx] = f2bf(tile[tx][r]);
    }
}

// ---------------- layernorm (PART=1: window-partition remap of input row) ----
template<int PART>
__global__ __launch_bounds__(256) void ln_kernel(
    const float* __restrict__ x, const float* __restrict__ gw,
    const float* __restrict__ gb, short* __restrict__ out) {
    int t = blockIdx.x;
    int row = PART ? nat_row(t) : t;
    const float* xr = x + (size_t)row * DIM;
    float v0 = xr[threadIdx.x], v1 = xr[threadIdx.x + 256], v2 = xr[threadIdx.x + 512];
    float s1 = v0 + v1 + v2;
    float s2 = v0 * v0 + v1 * v1 + v2 * v2;
#pragma unroll
    for (int o = 32; o > 0; o >>= 1) { s1 += __shfl_down(s1, o); s2 += __shfl_down(s2, o); }
    __shared__ float ws1[4], ws2[4];
    int wid = threadIdx.x >> 6, lane = threadIdx.x & 63;
    if (lane == 0) { ws1[wid] = s1; ws2[wid] = s2; }
    __syncthreads();
    s1 = ws1[0] + ws1[1] + ws1[2] + ws1[3];
    s2 = ws2[0] + ws2[1] + ws2[2] + ws2[3];
    float mean = s1 * (1.f / DIM);
    float var = s2 * (1.f / DIM) - mean * mean;
    float inv = rsqrtf(var + 1e-5f);
    short* orow = out + (size_t)t * DIM;
    orow[threadIdx.x]       = f2bf((v0 - mean) * inv * gw[threadIdx.x]       + gb[threadIdx.x]);
    orow[threadIdx.x + 256] = f2bf((v1 - mean) * inv * gw[threadIdx.x + 256] + gb[threadIdx.x + 256]);
    orow[threadIdx.x + 512] = f2bf((v2 - mean) * inv * gw[threadIdx.x + 512] + gb[threadIdx.x + 512]);
}

// ---------------- GEMM: C[M,N] = A[M,K] (bf16) @ BT[N,K]^T (bf16) -----------
enum { EPI_C = 0, EPI_PROJ = 1, EPI_GELU = 2, EPI_MLP2 = 3 };

template<int EPI, int K, int N>
__global__ __launch_bounds__(256) void gemm_kernel(
    const short* __restrict__ A, const short* __restrict__ BT,
    const float* __restrict__ bias,
    const float* __restrict__ x_in, float* __restrict__ out_f,
    short* __restrict__ out_b) {
    __shared__ short As[128 * 32];
    __shared__ short Bs[128 * 32];
    int tile_n = blockIdx.x, tile_m = blockIdx.y;
    int tid = threadIdx.x;
    int wid = tid >> 6, lane = tid & 63, lr = lane & 15, lg = lane >> 4;
    int wr = wid >> 1, wc = wid & 1;
    f32x4 acc[4][4] = {};
    const short* Arow = A + (size_t)(tile_m * 128) * K;
    const short* Brow = BT + (size_t)(tile_n * 128) * K;
    int c0 = wid * 2, c1 = wid * 2 + 1;
    int rl0 = c0 * 16 + (lane >> 2), rl1 = c1 * 16 + (lane >> 2);
    int sq0 = ((lane & 3) ^ ((rl0 >> 1) & 3)) * 8;
    int sq1 = ((lane & 3) ^ ((rl1 >> 1) & 3)) * 8;
    const short* gA0 = Arow + (size_t)rl0 * K + sq0;
    const short* gA1 = Arow + (size_t)rl1 * K + sq1;
    const short* gB0 = Brow + (size_t)rl0 * K + sq0;
    const short* gB1 = Brow + (size_t)rl1 * K + sq1;
#pragma unroll 1
    for (int k0 = 0; k0 < K; k0 += 32) {
        GLDS16(gA0 + k0, &As[c0 * 512]);
        GLDS16(gA1 + k0, &As[c1 * 512]);
        GLDS16(gB0 + k0, &Bs[c0 * 512]);
        GLDS16(gB1 + k0, &Bs[c1 * 512]);
        __syncthreads();
        s16x8 af[4], bfr[4];
#pragma unroll
        for (int m = 0; m < 4; m++) {
            int row = wr * 64 + m * 16 + lr;
            af[m] = *(const s16x8*)&As[row * 32 + ((lg ^ ((row >> 1) & 3)) << 3)];
        }
#pragma unroll
        for (int n = 0; n < 4; n++) {
            int row = wc * 64 + n * 16 + lr;
            bfr[n] = *(const s16x8*)&Bs[row * 32 + ((lg ^ ((row >> 1) & 3)) << 3)];
        }
#pragma unroll
        for (int m = 0; m < 4; m++)
#pragma unroll
            for (int n = 0; n < 4; n++)
                acc[m][n] = __builtin_amdgcn_mfma_f32_16x16x32_bf16(af[m], bfr[n], acc[m][n], 0, 0, 0);
        __syncthreads();
    }
#pragma unroll
    for (int m = 0; m < 4; m++)
#pragma unroll
        for (int n = 0; n < 4; n++)
#pragma unroll
            for (int r = 0; r < 4; r++) {
                int row = tile_m * 128 + wr * 64 + m * 16 + lg * 4 + r;
                int col = tile_n * 128 + wc * 64 + n * 16 + lr;
                float v = acc[m][n][r] + bias[col];
                if (EPI == EPI_C) {
                    out_b[(size_t)row * N + col] = f2bf(v);
                } else if (EPI == EPI_PROJ) {
                    int nr = nat_row(row);
                    out_f[(size_t)nr * DIM + col] = v + x_in[(size_t)nr * DIM + col];
                } else if (EPI == EPI_GELU) {
                    float g = 0.5f * v * (1.f + erff(v * 0.70710678118f));
                    out_b[(size_t)row * (size_t)N + col] = f2bf(g);
                } else { // EPI_MLP2
                    out_f[(size_t)row * DIM + col] += v;
                }
            }
}

// ---------------- V repack: qkv[t, 1536+h*64+d] -> vt[wh][d][tok] ----------
__global__ __launch_bounds__(256) void repack_vt(
    const short* __restrict__ qkv, short* __restrict__ vt) {
    __shared__ short tile[64][72];
    int ntb = blockIdx.x, wh = blockIdx.y;
    int win = wh / HEADS, h = wh % HEADS;
    const short* vbase = qkv + (size_t)(win * 512 + ntb * 64) * 2304 + 1536 + h * 64;
    int tid = threadIdx.x;
#pragma unroll
    for (int p = 0; p < 2; p++) {
        int idx = tid + p * 256;
        int tok = idx >> 3, vc = idx & 7;
        s16x8 v = *(const s16x8*)&vbase[(size_t)tok * 2304 + vc * 8];
#pragma unroll
        for (int j = 0; j < 8; j++) tile[vc * 8 + j][tok] = v[j];
    }
    __syncthreads();
#pragma unroll
    for (int p = 0; p < 2; p++) {
        int idx = tid + p * 256;
        int d = idx >> 3, vc = idx & 7;
        s16x8 o = *(const s16x8*)&tile[d][vc * 8];
        *(s16x8*)&vt[((size_t)wh * 64 + d) * 512 + ntb * 64 + vc * 8] = o;
    }
}

// ---------------- attention: per (q-tile of 64, window*head) ----------------
// K/V^T tiles staged in LDS via global_load_lds (double-buffered, pre-swizzled
// source: quad ^= row&7) so all frag ds_read_b128 are conflict-free. Ps uses
// the same XOR involution (write quad^(prow&7), read quad^(lr&7)).
__global__ __launch_bounds__(256) void attn_kernel(
    const short* __restrict__ qkv, const short* __restrict__ vt,
    const float* __restrict__ rpd, const float* __restrict__ rph,
    const float* __restrict__ rpw, short* __restrict__ out) {
    __shared__ float bd[64][8], bh[64][8], bw[64][8];
    __shared__ short Ps[4][16 * 64];
    __shared__ short Ks[2][64 * 64];
    __shared__ short Vs[2][64 * 64];
    int qt = blockIdx.x;   // 0..7
    int wh = blockIdx.y;   // 0..191
    int win = wh / HEADS, h = wh % HEADS;
    int qbase = qt * 64;
    const short* qp = qkv + (size_t)(win * 512) * 2304 + h * 64;  // row stride 2304
    const short* kp = qp + 768;
    const short* vp = vt + (size_t)wh * 64 * 512;
    int tid = threadIdx.x, wid = tid >> 6, lane = tid & 63, lr = lane & 15, lg = lane >> 4;

    // decomposed rel-pos bias tables for this block's 64 q rows
    for (int i = tid; i < 64 * 24; i += 256) {
        int qr = i / 24, e = i % 24;
        int tb = e >> 3, kidx = e & 7;
        int qtok = qbase + qr;
        int qc = (tb == 0) ? (qtok >> 6) : (tb == 1) ? ((qtok >> 3) & 7) : (qtok & 7);
        const float* R = ((tb == 0) ? rpd : (tb == 1) ? rph : rpw) + (size_t)(qc - kidx + 7) * 64;
        const short* qv = qp + (size_t)qtok * 2304;
        float s = 0.f;
#pragma unroll
        for (int c8 = 0; c8 < 8; c8++) {
            s16x8 q8 = *(const s16x8*)&qv[c8 * 8];
#pragma unroll
            for (int j = 0; j < 8; j++) s += bf2f(q8[j]) * R[c8 * 8 + j];
        }
        if (tb == 0) bd[qr][kidx] = s; else if (tb == 1) bh[qr][kidx] = s; else bw[qr][kidx] = s;
    }

    // staging geometry: chunk c = wid*64+lane (batch0), +256 (batch1);
    // row = c>>3 (0..63), quad p = c&7; source quad pre-swizzled by row&7
    int row0 = wid * 8 + (lane >> 3);         // 0..31 (batch0); batch1 = +32
    int swz = ((lane & 7) ^ (row0 & 7)) * 8;  // (row+32)&7 == row&7
    const short* kSrc0 = kp + (size_t)row0 * 2304 + swz;
    const short* kSrc1 = kp + (size_t)(row0 + 32) * 2304 + swz;
    const short* vSrc0 = vp + (size_t)row0 * 512 + swz;
    const short* vSrc1 = vp + (size_t)(row0 + 32) * 512 + swz;
    int ldsOff0 = wid * 512, ldsOff1 = 2048 + wid * 512;

    // Q frags (once)
    s16x8 aq[2];
    {
        size_t qoff = (size_t)(qbase + wid * 16 + lr) * 2304;
        aq[0] = *(const s16x8*)&qp[qoff + lg * 8];
        aq[1] = *(const s16x8*)&qp[qoff + 32 + lg * 8];
    }

    // stage tile 0
    GLDS16(kSrc0, &Ks[0][ldsOff0]);
    GLDS16(kSrc1, &Ks[0][ldsOff1]);
    GLDS16(vSrc0, &Vs[0][ldsOff0]);
    GLDS16(vSrc1, &Vs[0][ldsOff1]);
    __syncthreads();

    float m_run[4], l_run[4];
    f32x4 accO[4] = {};
#pragma unroll
    for (int r = 0; r < 4; r++) { m_run[r] = -1e30f; l_run[r] = 0.f; }
    int qr0 = wid * 16 + lg * 4;

#pragma unroll 1
    for (int kt = 0; kt < 8; kt++) {
        int cur = kt & 1;
        if (kt < 7) {  // prefetch next tile into the other buffer
            size_t kAdv = (size_t)(kt + 1) * 64 * 2304;
            int vAdv = (kt + 1) * 64;
            GLDS16(kSrc0 + kAdv, &Ks[cur ^ 1][ldsOff0]);
            GLDS16(kSrc1 + kAdv, &Ks[cur ^ 1][ldsOff1]);
            GLDS16(vSrc0 + vAdv, &Vs[cur ^ 1][ldsOff0]);
            GLDS16(vSrc1 + vAdv, &Vs[cur ^ 1][ldsOff1]);
        }
        f32x4 sa[4] = {};
#pragma unroll
        for (int kn = 0; kn < 4; kn++) {
            int krow = kn * 16 + lr;
            const short* kb_ = &Ks[cur][krow * 64];
            s16x8 bk0 = *(const s16x8*)&kb_[((lg ^ (krow & 7)) << 3)];
            s16x8 bk1 = *(const s16x8*)&kb_[(((4 + lg) ^ (krow & 7)) << 3)];
            sa[kn] = __builtin_amdgcn_mfma_f32_16x16x32_bf16(aq[0], bk0, sa[kn], 0, 0, 0);
            sa[kn] = __builtin_amdgcn_mfma_f32_16x16x32_bf16(aq[1], bk1, sa[kn], 0, 0, 0);
        }
        float sv[4][4], mx[4];
#pragma unroll
        for (int r = 0; r < 4; r++) mx[r] = -1e30f;
#pragma unroll
        for (int kn = 0; kn < 4; kn++) {
            int klocal = kn * 16 + lr;
            int kh_ = klocal >> 3, kw_ = klocal & 7;
#pragma unroll
            for (int r = 0; r < 4; r++) {
                float vv = sa[kn][r] * 0.125f + bd[qr0 + r][kt] + bh[qr0 + r][kh_] + bw[qr0 + r][kw_];
                sv[kn][r] = vv;
                mx[r] = fmaxf(mx[r], vv);
            }
        }
#pragma unroll
        for (int r = 0; r < 4; r++)
#pragma unroll
            for (int o = 1; o < 16; o <<= 1) mx[r] = fmaxf(mx[r], __shfl_xor(mx[r], o));
        float corr[4], tsum[4];
#pragma unroll
        for (int r = 0; r < 4; r++) {
            float nm = fmaxf(m_run[r], mx[r]);
            corr[r] = __expf(m_run[r] - nm);
            m_run[r] = nm;
            tsum[r] = 0.f;
        }
        float ps[4][4];
#pragma unroll
        for (int kn = 0; kn < 4; kn++)
#pragma unroll
            for (int r = 0; r < 4; r++) {
                float p = __expf(sv[kn][r] - m_run[r]);
                ps[kn][r] = p; tsum[r] += p;
            }
#pragma unroll
        for (int r = 0; r < 4; r++) {
#pragma unroll
            for (int o = 1; o < 16; o <<= 1) tsum[r] += __shfl_xor(tsum[r], o);
            l_run[r] = l_run[r] * corr[r] + tsum[r];
        }
#pragma unroll
        for (int n = 0; n < 4; n++)
#pragma unroll
            for (int r = 0; r < 4; r++) accO[n][r] *= corr[r];
#pragma unroll
        for (int kn = 0; kn < 4; kn++)
#pragma unroll
            for (int r = 0; r < 4; r++) {
                int prow = lg * 4 + r;
                int sw = (((kn * 2 + (lr >> 3)) ^ (prow & 7)) << 3) + (lr & 7);
                Ps[wid][prow * 64 + sw] = f2bf(ps[kn][r]);
            }
#pragma unroll
        for (int s2 = 0; s2 < 2; s2++) {
            s16x8 ap = *(const s16x8*)&Ps[wid][lr * 64 + (((s2 * 4 + lg) ^ (lr & 7)) << 3)];
#pragma unroll
            for (int n = 0; n < 4; n++) {
                int vrow = n * 16 + lr;
                s16x8 bv = *(const s16x8*)&Vs[cur][vrow * 64 + (((s2 * 4 + lg) ^ (vrow & 7)) << 3)];
                accO[n] = __builtin_amdgcn_mfma_f32_16x16x32_bf16(ap, bv, accO[n], 0, 0, 0);
            }
        }
        __syncthreads();   // prefetch landed; all waves done with buf[cur]
    }
    int tok = win * 512 + qbase + wid * 16 + lg * 4;
#pragma unroll
    for (int n = 0; n < 4; n++)
#pragma unroll
        for (int r = 0; r < 4; r++) {
            float o = accO[n][r] / l_run[r];
            out[(size_t)(tok + r) * DIM + h * 64 + n * 16 + lr] = f2bf(o);
        }
}

// ---------------- launch ----------------
extern "C" void kernel_launch(void* const* d_in, const int* in_sizes, int n_in,
                              void* d_out, int out_size, void* d_ws, size_t ws_size,
                              hipStream_t stream) {
    const float* x      = (const float*)d_in[0];
    const float* w_qkv  = (const float*)d_in[1];
    const float* b_qkv  = (const float*)d_in[2];
    const float* w_proj = (const float*)d_in[3];
    const float* b_proj = (const float*)d_in[4];
    const float* rpd    = (const float*)d_in[5];
    const float* rph    = (const float*)d_in[6];
    const float* rpw    = (const float*)d_in[7];
    const float* n1w    = (const float*)d_in[8];
    const float* n1b    = (const float*)d_in[9];
    const float* n2w    = (const float*)d_in[10];
    const float* n2b    = (const float*)d_in[11];
    const float* w1     = (const float*)d_in[12];
    const float* b1     = (const float*)d_in[13];
    const float* w2     = (const float*)d_in[14];
    const float* b2     = (const float*)d_in[15];
    float* out = (float*)d_out;
    char* ws = (char*)d_ws;
    size_t off = 0;
    auto alloc = [&](size_t bytes) { void* p = ws + off; off += (bytes + 255) & ~255ULL; return p; };
    short* wqkvT  = (short*)alloc((size_t)2304 * 768 * 2);
    short* wprojT = (short*)alloc((size_t)768 * 768 * 2);
    short* w1T    = (short*)alloc((size_t)3072 * 768 * 2);
    short* w2T    = (short*)alloc((size_t)768 * 3072 * 2);
    short* xn1    = (short*)alloc((size_t)8192 * 768 * 2);   // reused as attn-out
    short* qkvC   = (short*)alloc((size_t)8192 * 2304 * 2);
    short* vtb    = (short*)alloc((size_t)192 * 64 * 512 * 2);
    short* xn2    = (short*)alloc((size_t)8192 * 768 * 2);
    short* hid    = (short*)alloc((size_t)8192 * 3072 * 2);
    short* attnout = xn1;

    transpose_cvt<<<dim3(2304 / 32, 768 / 32), 256, 0, stream>>>(w_qkv, wqkvT, 768, 2304);
    transpose_cvt<<<dim3(768 / 32, 768 / 32), 256, 0, stream>>>(w_proj, wprojT, 768, 768);
    transpose_cvt<<<dim3(3072 / 32, 768 / 32), 256, 0, stream>>>(w1, w1T, 768, 3072);
    transpose_cvt<<<dim3(768 / 32, 3072 / 32), 256, 0, stream>>>(w2, w2T, 3072, 768);

    ln_kernel<1><<<8192, 256, 0, stream>>>(x, n1w, n1b, xn1);
    gemm_kernel<EPI_C, 768, 2304><<<dim3(18, 64), 256, 0, stream>>>(
        xn1, wqkvT, b_qkv, nullptr, nullptr, qkvC);
    repack_vt<<<dim3(8, 192), 256, 0, stream>>>(qkvC, vtb);
    attn_kernel<<<dim3(8, 192), 256, 0, stream>>>(qkvC, vtb, rpd, rph, rpw, attnout);
    gemm_kernel<EPI_PROJ, 768, 768><<<dim3(6, 64), 256, 0, stream>>>(
        attnout, wprojT, b_proj, x, out, nullptr);
    ln_kernel<0><<<8192, 256, 0, stream>>>(out, n2w, n2b, xn2);
    gemm_kernel<EPI_GELU, 768, 3072><<<dim3(24, 64), 256, 0, stream>>>(
        xn2, w1T, b1, nullptr, nullptr, hid);
    gemm_kernel<EPI_MLP2, 3072, 768><<<dim3(6, 64), 256, 0, stream>>>(
        hid, w2T, b2, nullptr, out, nullptr);
}

// Round 5
// 356.140 us; speedup vs baseline: 3.2640x; 1.1076x over previous
//
#include <hip/hip_runtime.h>
#include <hip/hip_bf16.h>
#include <math.h>

typedef short s16x8 __attribute__((ext_vector_type(8)));
typedef float f32x4 __attribute__((ext_vector_type(4)));
typedef int   s32x4 __attribute__((ext_vector_type(4)));

#define DIM 768
#define HEADS 12

static __device__ __forceinline__ short f2bf(float x) {
    union { float f; unsigned u; } v; v.f = x;
    unsigned r = (v.u + 0x7FFF + ((v.u >> 16) & 1)) >> 16;
    return (short)r;
}
static __device__ __forceinline__ float bf2f(short x) {
    union { unsigned u; float f; } v;
    v.u = ((unsigned)(unsigned short)x) << 16;
    return v.f;
}
// packed f32x2 -> bf16x2 (RNE), single HW instr; no builtin on gfx950
static __device__ __forceinline__ unsigned cvt_pk_bf16(float lo, float hi) {
    unsigned r;
    asm("v_cvt_pk_bf16_f32 %0, %1, %2" : "=v"(r) : "v"(lo), "v"(hi));
    return r;
}

// async global->LDS, 16B per lane, wave-uniform LDS base + lane*16
#define GLDS16(g, l) __builtin_amdgcn_global_load_lds( \
    (__attribute__((address_space(1))) void*)(g), \
    (__attribute__((address_space(3))) void*)(l), 16, 0, 0)

// partitioned token t (win*512+n) -> natural token index in [0, 8192)
static __device__ __forceinline__ int nat_row(int t) {
    int w = t >> 9, n = t & 511;
    int b = w >> 3, dO = (w >> 2) & 1, hO = (w >> 1) & 1, wO = w & 1;
    int di = n >> 6, hi = (n >> 3) & 7, wi = n & 7;
    int Dd = dO * 8 + di, Hh = hO * 8 + hi, Ww = wO * 8 + wi;
    return ((b * 16 + Dd) * 16 + Hh) * 16 + Ww;
}

// ---------------- weight transpose + fp32->bf16 ----------------
__global__ __launch_bounds__(256) void transpose_cvt(
    const float* __restrict__ in, short* __restrict__ out, int K, int N) {
    __shared__ float tile[32][33];
    int n0 = blockIdx.x * 32, k0 = blockIdx.y * 32;
    int tx = threadIdx.x & 31, ty = threadIdx.x >> 5;
#pragma unroll
    for (int j = 0; j < 4; j++) {
        int r = ty + j * 8;
        tile[r][tx] = in[(size_t)(k0 + r) * N + n0 + tx];
    }
    __syncthreads();
#pragma unroll
    for (int j = 0; j < 4; j++) {
        int r = ty + j * 8;
        out[(size_t)(n0 + r) * K + k0 + tx] = f2bf(tile[tx][r]);
    }
}

// ---------------- layernorm (PART=1: window-partition remap of input row) ----
template<int PART>
__global__ __launch_bounds__(256) void ln_kernel(
    const float* __restrict__ x, const float* __restrict__ gw,
    const float* __restrict__ gb, short* __restrict__ out) {
    int t = blockIdx.x;
    int row = PART ? nat_row(t) : t;
    const float* xr = x + (size_t)row * DIM;
    float v0 = xr[threadIdx.x], v1 = xr[threadIdx.x + 256], v2 = xr[threadIdx.x + 512];
    float s1 = v0 + v1 + v2;
    float s2 = v0 * v0 + v1 * v1 + v2 * v2;
#pragma unroll
    for (int o = 32; o > 0; o >>= 1) { s1 += __shfl_down(s1, o); s2 += __shfl_down(s2, o); }
    __shared__ float ws1[4], ws2[4];
    int wid = threadIdx.x >> 6, lane = threadIdx.x & 63;
    if (lane == 0) { ws1[wid] = s1; ws2[wid] = s2; }
    __syncthreads();
    s1 = ws1[0] + ws1[1] + ws1[2] + ws1[3];
    s2 = ws2[0] + ws2[1] + ws2[2] + ws2[3];
    float mean = s1 * (1.f / DIM);
    float var = s2 * (1.f / DIM) - mean * mean;
    float inv = rsqrtf(var + 1e-5f);
    short* orow = out + (size_t)t * DIM;
    orow[threadIdx.x]       = f2bf((v0 - mean) * inv * gw[threadIdx.x]       + gb[threadIdx.x]);
    orow[threadIdx.x + 256] = f2bf((v1 - mean) * inv * gw[threadIdx.x + 256] + gb[threadIdx.x + 256]);
    orow[threadIdx.x + 512] = f2bf((v2 - mean) * inv * gw[threadIdx.x + 512] + gb[threadIdx.x + 512]);
}

// ---------------- GEMM: C[M,N] = A[M,K] (bf16) @ BT[N,K]^T (bf16) -----------
// BK=64: half the barriers of BK=32, 32 MFMA per k-step. 8-slot XOR source
// pre-swizzle (slot ^= row&7) keeps frag ds_read_b128 conflict-free.
enum { EPI_C = 0, EPI_PROJ = 1, EPI_GELU = 2, EPI_MLP2 = 3 };

template<int EPI, int K, int N>
__global__ __launch_bounds__(256) void gemm_kernel(
    const short* __restrict__ A, const short* __restrict__ BT,
    const float* __restrict__ bias,
    const float* __restrict__ x_in, float* __restrict__ out_f,
    short* __restrict__ out_b) {
    __shared__ short As[128 * 64];
    __shared__ short Bs[128 * 64];
    int tile_n = blockIdx.x, tile_m = blockIdx.y;
    int tid = threadIdx.x;
    int wid = tid >> 6, lane = tid & 63, lr = lane & 15, lg = lane >> 4;
    int wr = wid >> 1, wc = wid & 1;
    f32x4 acc[4][4] = {};
    const short* Arow = A + (size_t)(tile_m * 128) * K;
    const short* Brow = BT + (size_t)(tile_n * 128) * K;
    // staging: chunk c = i*256 + wid*64 + lane -> LDS bytes c*16;
    // row = c>>3, slot = c&7; source slot = (lane&7) ^ (row&7), row&7 = lane>>3
    int swzS = ((lane & 7) ^ (lane >> 3)) * 8;
    int rbase = wid * 8 + (lane >> 3);
    const short* gA[4]; const short* gB[4]; int ldsO[4];
#pragma unroll
    for (int i = 0; i < 4; i++) {
        int row = i * 32 + rbase;
        gA[i] = Arow + (size_t)row * K + swzS;
        gB[i] = Brow + (size_t)row * K + swzS;
        ldsO[i] = (i * 256 + wid * 64) * 8;
    }
#pragma unroll 1
    for (int k0 = 0; k0 < K; k0 += 64) {
#pragma unroll
        for (int i = 0; i < 4; i++) {
            GLDS16(gA[i] + k0, &As[ldsO[i]]);
            GLDS16(gB[i] + k0, &Bs[ldsO[i]]);
        }
        __syncthreads();
#pragma unroll
        for (int h = 0; h < 2; h++) {
            s16x8 af[4], bfr[4];
#pragma unroll
            for (int m = 0; m < 4; m++) {
                int row = wr * 64 + m * 16 + lr;
                af[m] = *(const s16x8*)&As[row * 64 + (((h * 4 + lg) ^ (lr & 7)) << 3)];
            }
#pragma unroll
            for (int n = 0; n < 4; n++) {
                int row = wc * 64 + n * 16 + lr;
                bfr[n] = *(const s16x8*)&Bs[row * 64 + (((h * 4 + lg) ^ (lr & 7)) << 3)];
            }
#pragma unroll
            for (int m = 0; m < 4; m++)
#pragma unroll
                for (int n = 0; n < 4; n++)
                    acc[m][n] = __builtin_amdgcn_mfma_f32_16x16x32_bf16(af[m], bfr[n], acc[m][n], 0, 0, 0);
        }
        __syncthreads();
    }
#pragma unroll
    for (int m = 0; m < 4; m++)
#pragma unroll
        for (int n = 0; n < 4; n++)
#pragma unroll
            for (int r = 0; r < 4; r++) {
                int row = tile_m * 128 + wr * 64 + m * 16 + lg * 4 + r;
                int col = tile_n * 128 + wc * 64 + n * 16 + lr;
                float v = acc[m][n][r] + bias[col];
                if (EPI == EPI_C) {
                    out_b[(size_t)row * N + col] = f2bf(v);
                } else if (EPI == EPI_PROJ) {
                    int nr = nat_row(row);
                    out_f[(size_t)nr * DIM + col] = v + x_in[(size_t)nr * DIM + col];
                } else if (EPI == EPI_GELU) {
                    float g = 0.5f * v * (1.f + erff(v * 0.70710678118f));
                    out_b[(size_t)row * (size_t)N + col] = f2bf(g);
                } else { // EPI_MLP2
                    out_f[(size_t)row * DIM + col] += v;
                }
            }
}

// ---------------- V repack: qkv[t, 1536+h*64+d] -> vt[wh][d][tok] ----------
__global__ __launch_bounds__(256) void repack_vt(
    const short* __restrict__ qkv, short* __restrict__ vt) {
    __shared__ short tile[64][72];
    int ntb = blockIdx.x, wh = blockIdx.y;
    int win = wh / HEADS, h = wh % HEADS;
    const short* vbase = qkv + (size_t)(win * 512 + ntb * 64) * 2304 + 1536 + h * 64;
    int tid = threadIdx.x;
#pragma unroll
    for (int p = 0; p < 2; p++) {
        int idx = tid + p * 256;
        int tok = idx >> 3, vc = idx & 7;
        s16x8 v = *(const s16x8*)&vbase[(size_t)tok * 2304 + vc * 8];
#pragma unroll
        for (int j = 0; j < 8; j++) tile[vc * 8 + j][tok] = v[j];
    }
    __syncthreads();
#pragma unroll
    for (int p = 0; p < 2; p++) {
        int idx = tid + p * 256;
        int d = idx >> 3, vc = idx & 7;
        s16x8 o = *(const s16x8*)&tile[d][vc * 8];
        *(s16x8*)&vt[((size_t)wh * 64 + d) * 512 + ntb * 64 + vc * 8] = o;
    }
}

// ---------------- attention (swapped-operand): S^T = mfma(K, Q) ------------
// Each lane owns one q-row (q = lane&15): softmax state is scalar, row
// reduce = in-lane tree + 2 shuffles. P stays in registers (cvt_pk pairs),
// redistributed to PV B-frags via ds_bpermute. PV computes O^T (A = V^T).
__global__ __launch_bounds__(256) void attn_kernel(
    const short* __restrict__ qkv, const short* __restrict__ vt,
    const float* __restrict__ rpd, const float* __restrict__ rph,
    const float* __restrict__ rpw, short* __restrict__ out) {
    __shared__ float bd[64][8], bh[64][8], bw[64][8];   // pre-scaled by log2(e)
    __shared__ short Ks[2][64 * 64];
    __shared__ short Vs[2][64 * 64];
    int qt = blockIdx.x;   // 0..7
    int wh = blockIdx.y;   // 0..191
    int win = wh / HEADS, h = wh % HEADS;
    int qbase = qt * 64;
    const short* qp = qkv + (size_t)(win * 512) * 2304 + h * 64;  // row stride 2304
    const short* kp = qp + 768;
    const short* vp = vt + (size_t)wh * 64 * 512;
    int tid = threadIdx.x, wid = tid >> 6, lane = tid & 63, lr = lane & 15, lg = lane >> 4;
    const float LOG2E = 1.4426950408889634f;

    // decomposed rel-pos bias tables (log2-domain) for this block's 64 q rows
    for (int i = tid; i < 64 * 24; i += 256) {
        int qr = i / 24, e = i % 24;
        int tb = e >> 3, kidx = e & 7;
        int qtok = qbase + qr;
        int qc = (tb == 0) ? (qtok >> 6) : (tb == 1) ? ((qtok >> 3) & 7) : (qtok & 7);
        const float* R = ((tb == 0) ? rpd : (tb == 1) ? rph : rpw) + (size_t)(qc - kidx + 7) * 64;
        const short* qv = qp + (size_t)qtok * 2304;
        float s = 0.f;
#pragma unroll
        for (int c8 = 0; c8 < 8; c8++) {
            s16x8 q8 = *(const s16x8*)&qv[c8 * 8];
#pragma unroll
            for (int j = 0; j < 8; j++) s += bf2f(q8[j]) * R[c8 * 8 + j];
        }
        s *= LOG2E;
        if (tb == 0) bd[qr][kidx] = s; else if (tb == 1) bh[qr][kidx] = s; else bw[qr][kidx] = s;
    }

    // staging: row0 = wid*8 + (lane>>3) (0..31; +32 batch1); slot swizzle row&7
    int row0 = wid * 8 + (lane >> 3);
    int swz = ((lane & 7) ^ (row0 & 7)) * 8;
    const short* kSrc0 = kp + (size_t)row0 * 2304 + swz;
    const short* kSrc1 = kp + (size_t)(row0 + 32) * 2304 + swz;
    const short* vSrc0 = vp + (size_t)row0 * 512 + swz;
    const short* vSrc1 = vp + (size_t)(row0 + 32) * 512 + swz;
    int ldsOff0 = wid * 512, ldsOff1 = 2048 + wid * 512;

    // Q B-frags (once): col q = lr, k-dim c = 8*lg+j (+32)
    s16x8 aq[2];
    {
        size_t qoff = (size_t)(qbase + wid * 16 + lr) * 2304;
        aq[0] = *(const s16x8*)&qp[qoff + lg * 8];
        aq[1] = *(const s16x8*)&qp[qoff + 32 + lg * 8];
    }

    GLDS16(kSrc0, &Ks[0][ldsOff0]);
    GLDS16(kSrc1, &Ks[0][ldsOff1]);
    GLDS16(vSrc0, &Vs[0][ldsOff0]);
    GLDS16(vSrc1, &Vs[0][ldsOff1]);
    __syncthreads();

    float m_run = -1e30f, l_run = 0.f;
    f32x4 accO[4] = {};
    int qr = wid * 16 + lr;
    int sel = lg >> 1;                  // which kn-pair this lane's B-frag needs
    int srcA = (2 * (lane & 1 ? 0 : 0) , 0); (void)srcA;
    const float SC = 0.125f * LOG2E;

#pragma unroll 1
    for (int kt = 0; kt < 8; kt++) {
        int cur = kt & 1;
        if (kt < 7) {
            size_t kAdv = (size_t)(kt + 1) * 64 * 2304;
            int vAdv = (kt + 1) * 64;
            GLDS16(kSrc0 + kAdv, &Ks[cur ^ 1][ldsOff0]);
            GLDS16(kSrc1 + kAdv, &Ks[cur ^ 1][ldsOff1]);
            GLDS16(vSrc0 + vAdv, &Vs[cur ^ 1][ldsOff0]);
            GLDS16(vSrc1 + vAdv, &Vs[cur ^ 1][ldsOff1]);
        }
        // S^T: A = K rows (ktok_local = kn*16+lr), B = Q
        f32x4 sa[4];
#pragma unroll
        for (int kn = 0; kn < 4; kn++) {
            int krow = kn * 16 + lr;
            const short* kb_ = &Ks[cur][krow * 64];
            s16x8 ak0 = *(const s16x8*)&kb_[((lg ^ (krow & 7)) << 3)];
            s16x8 ak1 = *(const s16x8*)&kb_[(((4 + lg) ^ (krow & 7)) << 3)];
            f32x4 z = {};
            z = __builtin_amdgcn_mfma_f32_16x16x32_bf16(ak0, aq[0], z, 0, 0, 0);
            z = __builtin_amdgcn_mfma_f32_16x16x32_bf16(ak1, aq[1], z, 0, 0, 0);
            sa[kn] = z;
        }
        // bias (log2-domain): k_local = kn*16 + lg*4 + r
        float bdv = bd[qr][kt];
        float bb[4], bwv[4];
#pragma unroll
        for (int kn = 0; kn < 4; kn++) bb[kn] = bdv + bh[qr][2 * kn + sel];
#pragma unroll
        for (int r = 0; r < 4; r++) bwv[r] = bw[qr][4 * (lg & 1) + r];
        float sv[4][4], mx = -1e30f;
#pragma unroll
        for (int kn = 0; kn < 4; kn++)
#pragma unroll
            for (int r = 0; r < 4; r++) {
                float vv = sa[kn][r] * SC + (bb[kn] + bwv[r]);
                sv[kn][r] = vv;
                mx = fmaxf(mx, vv);
            }
        mx = fmaxf(mx, __shfl_xor(mx, 16));
        mx = fmaxf(mx, __shfl_xor(mx, 32));
        float nm = fmaxf(m_run, mx);
        float corr = exp2f(m_run - nm);
        m_run = nm;
        float p[4][4], tsum = 0.f;
#pragma unroll
        for (int kn = 0; kn < 4; kn++)
#pragma unroll
            for (int r = 0; r < 4; r++) {
                float pv = exp2f(sv[kn][r] - nm);
                p[kn][r] = pv; tsum += pv;
            }
        tsum += __shfl_xor(tsum, 16);
        tsum += __shfl_xor(tsum, 32);
        l_run = l_run * corr + tsum;
#pragma unroll
        for (int n = 0; n < 4; n++)
#pragma unroll
            for (int r = 0; r < 4; r++) accO[n][r] *= corr;
        // pack p into bf16 pairs: u[kn][j] = k {kn*16+lg*4+2j, +1}
        unsigned u[4][2];
#pragma unroll
        for (int kn = 0; kn < 4; kn++) {
            u[kn][0] = cvt_pk_bf16(p[kn][0], p[kn][1]);
            u[kn][1] = cvt_pk_bf16(p[kn][2], p[kn][3]);
        }
        // redistribute to PV B-frags: reg t of half s2 holds k = 32*s2+8*lg+2t,+1
        // source lane = (2*(lg&1)+(t>>1))*16 + lr, register u[2*s2+(lg>>1)][t&1]
        s32x4 bfr2[2];
#pragma unroll
        for (int s2 = 0; s2 < 2; s2++)
#pragma unroll
            for (int tp = 0; tp < 2; tp++) {
                int src = (2 * (lg & 1) + tp) * 16 + lr;
#pragma unroll
                for (int j = 0; j < 2; j++) {
                    int a0 = __shfl((int)u[2 * s2][j], src);
                    int a1 = __shfl((int)u[2 * s2 + 1][j], src);
                    bfr2[s2][tp * 2 + j] = sel ? a1 : a0;
                }
            }
        // PV: O^T[d, q]; A = V^T (row d = n*16+lr, k tokens), B = P^T
#pragma unroll
        for (int s2 = 0; s2 < 2; s2++) {
            s16x8 pb = *(s16x8*)&bfr2[s2];
#pragma unroll
            for (int n = 0; n < 4; n++) {
                int vrow = n * 16 + lr;
                s16x8 av = *(const s16x8*)&Vs[cur][vrow * 64 + (((s2 * 4 + lg) ^ (vrow & 7)) << 3)];
                accO[n] = __builtin_amdgcn_mfma_f32_16x16x32_bf16(av, pb, accO[n], 0, 0, 0);
            }
        }
        __syncthreads();
    }
    // epilogue: lane owns q-row (tok) cols d = n*16 + 4*lg + r
    float inv = __builtin_amdgcn_rcpf(l_run);
    int tok = win * 512 + qbase + wid * 16 + lr;
    short* orow = out + (size_t)tok * DIM + h * 64;
#pragma unroll
    for (int n = 0; n < 4; n++)
#pragma unroll
        for (int j = 0; j < 2; j++) {
            unsigned uo = cvt_pk_bf16(accO[n][2 * j] * inv, accO[n][2 * j + 1] * inv);
            *(unsigned*)&orow[n * 16 + 4 * lg + 2 * j] = uo;
        }
}

// ---------------- launch ----------------
extern "C" void kernel_launch(void* const* d_in, const int* in_sizes, int n_in,
                              void* d_out, int out_size, void* d_ws, size_t ws_size,
                              hipStream_t stream) {
    const float* x      = (const float*)d_in[0];
    const float* w_qkv  = (const float*)d_in[1];
    const float* b_qkv  = (const float*)d_in[2];
    const float* w_proj = (const float*)d_in[3];
    const float* b_proj = (const float*)d_in[4];
    const float* rpd    = (const float*)d_in[5];
    const float* rph    = (const float*)d_in[6];
    const float* rpw    = (const float*)d_in[7];
    const float* n1w    = (const float*)d_in[8];
    const float* n1b    = (const float*)d_in[9];
    const float* n2w    = (const float*)d_in[10];
    const float* n2b    = (const float*)d_in[11];
    const float* w1     = (const float*)d_in[12];
    const float* b1     = (const float*)d_in[13];
    const float* w2     = (const float*)d_in[14];
    const float* b2     = (const float*)d_in[15];
    float* out = (float*)d_out;
    char* ws = (char*)d_ws;
    size_t off = 0;
    auto alloc = [&](size_t bytes) { void* p = ws + off; off += (bytes + 255) & ~255ULL; return p; };
    short* wqkvT  = (short*)alloc((size_t)2304 * 768 * 2);
    short* wprojT = (short*)alloc((size_t)768 * 768 * 2);
    short* w1T    = (short*)alloc((size_t)3072 * 768 * 2);
    short* w2T    = (short*)alloc((size_t)768 * 3072 * 2);
    short* xn1    = (short*)alloc((size_t)8192 * 768 * 2);   // reused as attn-out
    short* qkvC   = (short*)alloc((size_t)8192 * 2304 * 2);
    short* vtb    = (short*)alloc((size_t)192 * 64 * 512 * 2);
    short* xn2    = (short*)alloc((size_t)8192 * 768 * 2);
    short* hid    = (short*)alloc((size_t)8192 * 3072 * 2);
    short* attnout = xn1;

    transpose_cvt<<<dim3(2304 / 32, 768 / 32), 256, 0, stream>>>(w_qkv, wqkvT, 768, 2304);
    transpose_cvt<<<dim3(768 / 32, 768 / 32), 256, 0, stream>>>(w_proj, wprojT, 768, 768);
    transpose_cvt<<<dim3(3072 / 32, 768 / 32), 256, 0, stream>>>(w1, w1T, 768, 3072);
    transpose_cvt<<<dim3(768 / 32, 3072 / 32), 256, 0, stream>>>(w2, w2T, 3072, 768);

    ln_kernel<1><<<8192, 256, 0, stream>>>(x, n1w, n1b, xn1);
    gemm_kernel<EPI_C, 768, 2304><<<dim3(18, 64), 256, 0, stream>>>(
        xn1, wqkvT, b_qkv, nullptr, nullptr, qkvC);
    repack_vt<<<dim3(8, 192), 256, 0, stream>>>(qkvC, vtb);
    attn_kernel<<<dim3(8, 192), 256, 0, stream>>>(qkvC, vtb, rpd, rph, rpw, attnout);
    gemm_kernel<EPI_PROJ, 768, 768><<<dim3(6, 64), 256, 0, stream>>>(
        attnout, wprojT, b_proj, x, out, nullptr);
    ln_kernel<0><<<8192, 256, 0, stream>>>(out, n2w, n2b, xn2);
    gemm_kernel<EPI_GELU, 768, 3072><<<dim3(24, 64), 256, 0, stream>>>(
        xn2, w1T, b1, nullptr, nullptr, hid);
    gemm_kernel<EPI_MLP2, 3072, 768><<<dim3(6, 64), 256, 0, stream>>>(
        hid, w2T, b2, nullptr, out, nullptr);
}

// Round 6
// 300.645 us; speedup vs baseline: 3.8665x; 1.1846x over previous
//
#include <hip/hip_runtime.h>
#include <hip/hip_bf16.h>
#include <math.h>

typedef short s16x8 __attribute__((ext_vector_type(8)));
typedef float f32x4 __attribute__((ext_vector_type(4)));
typedef int   s32x4 __attribute__((ext_vector_type(4)));

#define DIM 768
#define HEADS 12

static __device__ __forceinline__ short f2bf(float x) {
    union { float f; unsigned u; } v; v.f = x;
    unsigned r = (v.u + 0x7FFF + ((v.u >> 16) & 1)) >> 16;
    return (short)r;
}
static __device__ __forceinline__ float bf2f(short x) {
    union { unsigned u; float f; } v;
    v.u = ((unsigned)(unsigned short)x) << 16;
    return v.f;
}
// packed f32x2 -> bf16x2 (RNE), single HW instr; no builtin on gfx950
static __device__ __forceinline__ unsigned cvt_pk_bf16(float lo, float hi) {
    unsigned r;
    asm("v_cvt_pk_bf16_f32 %0, %1, %2" : "=v"(r) : "v"(lo), "v"(hi));
    return r;
}

// async global->LDS, 16B per lane, wave-uniform LDS base + lane*16
#define GLDS16(g, l) __builtin_amdgcn_global_load_lds( \
    (__attribute__((address_space(1))) void*)(g), \
    (__attribute__((address_space(3))) void*)(l), 16, 0, 0)

// partitioned token t (win*512+n) -> natural token index in [0, 8192)
static __device__ __forceinline__ int nat_row(int t) {
    int w = t >> 9, n = t & 511;
    int b = w >> 3, dO = (w >> 2) & 1, hO = (w >> 1) & 1, wO = w & 1;
    int di = n >> 6, hi = (n >> 3) & 7, wi = n & 7;
    int Dd = dO * 8 + di, Hh = hO * 8 + hi, Ww = wO * 8 + wi;
    return ((b * 16 + Dd) * 16 + Hh) * 16 + Ww;
}

// ---------------- weight transpose + fp32->bf16 ----------------
__global__ __launch_bounds__(256) void transpose_cvt(
    const float* __restrict__ in, short* __restrict__ out, int K, int N) {
    __shared__ float tile[32][33];
    int n0 = blockIdx.x * 32, k0 = blockIdx.y * 32;
    int tx = threadIdx.x & 31, ty = threadIdx.x >> 5;
#pragma unroll
    for (int j = 0; j < 4; j++) {
        int r = ty + j * 8;
        tile[r][tx] = in[(size_t)(k0 + r) * N + n0 + tx];
    }
    __syncthreads();
#pragma unroll
    for (int j = 0; j < 4; j++) {
        int r = ty + j * 8;
        out[(size_t)(n0 + r) * K + k0 + tx] = f2bf(tile[tx][r]);
    }
}

// ---------------- layernorm (PART=1: window-partition remap of input row) ----
template<int PART>
__global__ __launch_bounds__(256) void ln_kernel(
    const float* __restrict__ x, const float* __restrict__ gw,
    const float* __restrict__ gb, short* __restrict__ out) {
    int t = blockIdx.x;
    int row = PART ? nat_row(t) : t;
    const float* xr = x + (size_t)row * DIM;
    float v0 = xr[threadIdx.x], v1 = xr[threadIdx.x + 256], v2 = xr[threadIdx.x + 512];
    float s1 = v0 + v1 + v2;
    float s2 = v0 * v0 + v1 * v1 + v2 * v2;
#pragma unroll
    for (int o = 32; o > 0; o >>= 1) { s1 += __shfl_down(s1, o); s2 += __shfl_down(s2, o); }
    __shared__ float ws1[4], ws2[4];
    int wid = threadIdx.x >> 6, lane = threadIdx.x & 63;
    if (lane == 0) { ws1[wid] = s1; ws2[wid] = s2; }
    __syncthreads();
    s1 = ws1[0] + ws1[1] + ws1[2] + ws1[3];
    s2 = ws2[0] + ws2[1] + ws2[2] + ws2[3];
    float mean = s1 * (1.f / DIM);
    float var = s2 * (1.f / DIM) - mean * mean;
    float inv = rsqrtf(var + 1e-5f);
    short* orow = out + (size_t)t * DIM;
    orow[threadIdx.x]       = f2bf((v0 - mean) * inv * gw[threadIdx.x]       + gb[threadIdx.x]);
    orow[threadIdx.x + 256] = f2bf((v1 - mean) * inv * gw[threadIdx.x + 256] + gb[threadIdx.x + 256]);
    orow[threadIdx.x + 512] = f2bf((v2 - mean) * inv * gw[threadIdx.x + 512] + gb[threadIdx.x + 512]);
}

// ---------------- GEMM: C[M,N] = A[M,K] (bf16) @ BT[N,K]^T (bf16) -----------
enum { EPI_C = 0, EPI_PROJ = 1, EPI_GELU = 2, EPI_MLP2 = 3 };

template<int EPI, int K, int N>
__global__ __launch_bounds__(256) void gemm_kernel(
    const short* __restrict__ A, const short* __restrict__ BT,
    const float* __restrict__ bias,
    const float* __restrict__ x_in, float* __restrict__ out_f,
    short* __restrict__ out_b) {
    __shared__ short As[128 * 64];
    __shared__ short Bs[128 * 64];
    int tile_n = blockIdx.x, tile_m = blockIdx.y;
    int tid = threadIdx.x;
    int wid = tid >> 6, lane = tid & 63, lr = lane & 15, lg = lane >> 4;
    int wr = wid >> 1, wc = wid & 1;
    f32x4 acc[4][4] = {};
    const short* Arow = A + (size_t)(tile_m * 128) * K;
    const short* Brow = BT + (size_t)(tile_n * 128) * K;
    int swzS = ((lane & 7) ^ (lane >> 3)) * 8;
    int rbase = wid * 8 + (lane >> 3);
    const short* gA[4]; const short* gB[4]; int ldsO[4];
#pragma unroll
    for (int i = 0; i < 4; i++) {
        int row = i * 32 + rbase;
        gA[i] = Arow + (size_t)row * K + swzS;
        gB[i] = Brow + (size_t)row * K + swzS;
        ldsO[i] = (i * 256 + wid * 64) * 8;
    }
#pragma unroll 1
    for (int k0 = 0; k0 < K; k0 += 64) {
#pragma unroll
        for (int i = 0; i < 4; i++) {
            GLDS16(gA[i] + k0, &As[ldsO[i]]);
            GLDS16(gB[i] + k0, &Bs[ldsO[i]]);
        }
        __syncthreads();
#pragma unroll
        for (int h = 0; h < 2; h++) {
            s16x8 af[4], bfr[4];
#pragma unroll
            for (int m = 0; m < 4; m++) {
                int row = wr * 64 + m * 16 + lr;
                af[m] = *(const s16x8*)&As[row * 64 + (((h * 4 + lg) ^ (lr & 7)) << 3)];
            }
#pragma unroll
            for (int n = 0; n < 4; n++) {
                int row = wc * 64 + n * 16 + lr;
                bfr[n] = *(const s16x8*)&Bs[row * 64 + (((h * 4 + lg) ^ (lr & 7)) << 3)];
            }
#pragma unroll
            for (int m = 0; m < 4; m++)
#pragma unroll
                for (int n = 0; n < 4; n++)
                    acc[m][n] = __builtin_amdgcn_mfma_f32_16x16x32_bf16(af[m], bfr[n], acc[m][n], 0, 0, 0);
        }
        __syncthreads();
    }
#pragma unroll
    for (int m = 0; m < 4; m++)
#pragma unroll
        for (int n = 0; n < 4; n++)
#pragma unroll
            for (int r = 0; r < 4; r++) {
                int row = tile_m * 128 + wr * 64 + m * 16 + lg * 4 + r;
                int col = tile_n * 128 + wc * 64 + n * 16 + lr;
                float v = acc[m][n][r] + bias[col];
                if (EPI == EPI_C) {
                    out_b[(size_t)row * N + col] = f2bf(v);
                } else if (EPI == EPI_PROJ) {
                    int nr = nat_row(row);
                    out_f[(size_t)nr * DIM + col] = v + x_in[(size_t)nr * DIM + col];
                } else if (EPI == EPI_GELU) {
                    float g = 0.5f * v * (1.f + erff(v * 0.70710678118f));
                    out_b[(size_t)row * (size_t)N + col] = f2bf(g);
                } else { // EPI_MLP2
                    out_f[(size_t)row * DIM + col] += v;
                }
            }
}

// ---------------- V repack: qkv[t, 1536+h*64+d] -> vt[wh][d][tok] ----------
__global__ __launch_bounds__(256) void repack_vt(
    const short* __restrict__ qkv, short* __restrict__ vt) {
    __shared__ short tile[64][72];
    int ntb = blockIdx.x, wh = blockIdx.y;
    int win = wh / HEADS, h = wh % HEADS;
    const short* vbase = qkv + (size_t)(win * 512 + ntb * 64) * 2304 + 1536 + h * 64;
    int tid = threadIdx.x;
#pragma unroll
    for (int p = 0; p < 2; p++) {
        int idx = tid + p * 256;
        int tok = idx >> 3, vc = idx & 7;
        s16x8 v = *(const s16x8*)&vbase[(size_t)tok * 2304 + vc * 8];
#pragma unroll
        for (int j = 0; j < 8; j++) tile[vc * 8 + j][tok] = v[j];
    }
    __syncthreads();
#pragma unroll
    for (int p = 0; p < 2; p++) {
        int idx = tid + p * 256;
        int d = idx >> 3, vc = idx & 7;
        s16x8 o = *(const s16x8*)&tile[d][vc * 8];
        *(s16x8*)&vt[((size_t)wh * 64 + d) * 512 + ntb * 64 + vc * 8] = o;
    }
}

// ---------------- attention: q-tile 128 (2 groups/wave), MFMA bias prologue -
// S^T = mfma(K, Q): lane owns one q-row per group -> scalar softmax state.
// Bias tables computed via MFMA (G = R_sel @ q^T) reusing Q frags; stored
// k-major [8][128] for conflict-free reads. K/V staged via global_load_lds
// (double-buffered, pre-swizzled source). P kept in registers (cvt_pk +
// shuffle redistribute). PV computes O^T with V-frags shared across groups.
__global__ __launch_bounds__(256) void attn_kernel(
    const short* __restrict__ qkv, const short* __restrict__ vt,
    const float* __restrict__ rpd, const float* __restrict__ rph,
    const float* __restrict__ rpw, short* __restrict__ out) {
    __shared__ float bdT[8][128], bhT[8][128], bwT[8][128];  // log2-domain
    __shared__ short Rs[48 * 64];
    __shared__ short Ks[2][64 * 64];
    __shared__ short Vs[2][64 * 64];
    int qt2 = blockIdx.x;  // 0..3 (q rows qt2*128 .. +127)
    int wh = blockIdx.y;   // 0..191
    int win = wh / HEADS, h = wh % HEADS;
    int qbase = qt2 * 128;
    const short* qp = qkv + (size_t)(win * 512) * 2304 + h * 64;  // row stride 2304
    const short* kp = qp + 768;
    const short* vp = vt + (size_t)wh * 64 * 512;
    int tid = threadIdx.x, wid = tid >> 6, lane = tid & 63, lr = lane & 15, lg = lane >> 4;
    const float LOG2E = 1.4426950408889634f;

    // Q B-frags for both groups (g*64 row offset)
    s16x8 aq[2][2];
#pragma unroll
    for (int g = 0; g < 2; g++) {
        size_t qoff = (size_t)(qbase + g * 64 + wid * 16 + lr) * 2304;
        aq[g][0] = *(const s16x8*)&qp[qoff + lg * 8];
        aq[g][1] = *(const s16x8*)&qp[qoff + 32 + lg * 8];
    }

    // stage R rows (log2-scaled, XOR-swizzled): 0..8 = Rd[qt2*2+j],
    // 16..30 = Rh[j], 32..46 = Rw[j]; others zero
    for (int i = tid; i < 48 * 64; i += 256) {
        int row = i >> 6, c = i & 63;
        float v = 0.f;
        if (row < 9)                     v = rpd[(qt2 * 2 + row) * 64 + c];
        else if (row >= 16 && row < 31)  v = rph[(row - 16) * 64 + c];
        else if (row >= 32 && row < 47)  v = rpw[(row - 32) * 64 + c];
        Rs[row * 64 + ((((c >> 3) ^ (row & 7)) << 3) | (c & 7))] = f2bf(v * LOG2E);
    }
    __syncthreads();

    // K/V staging geometry (row0 0..31, +32 batch1; slot swizzle row&7)
    int row0 = wid * 8 + (lane >> 3);
    int swz = ((lane & 7) ^ (row0 & 7)) * 8;
    const short* kSrc0 = kp + (size_t)row0 * 2304 + swz;
    const short* kSrc1 = kp + (size_t)(row0 + 32) * 2304 + swz;
    const short* vSrc0 = vp + (size_t)row0 * 512 + swz;
    const short* vSrc1 = vp + (size_t)(row0 + 32) * 512 + swz;
    int ldsOff0 = wid * 512, ldsOff1 = 2048 + wid * 512;

    // issue tile-0 staging; bias MFMA below overlaps the DMA
    GLDS16(kSrc0, &Ks[0][ldsOff0]);
    GLDS16(kSrc1, &Ks[0][ldsOff1]);
    GLDS16(vSrc0, &Vs[0][ldsOff0]);
    GLDS16(vSrc1, &Vs[0][ldsOff1]);

    // bias via MFMA: G[tile][g] -> lane holds G[tile*16+lg*4+r][its q-col lr]
    {
        f32x4 G[3][2];
#pragma unroll
        for (int t = 0; t < 3; t++) {
            int arow = t * 16 + lr;
            s16x8 a0 = *(const s16x8*)&Rs[arow * 64 + ((lg ^ (arow & 7)) << 3)];
            s16x8 a1 = *(const s16x8*)&Rs[arow * 64 + (((4 + lg) ^ (arow & 7)) << 3)];
#pragma unroll
            for (int g = 0; g < 2; g++) {
                f32x4 z = {};
                z = __builtin_amdgcn_mfma_f32_16x16x32_bf16(a0, aq[g][0], z, 0, 0, 0);
                z = __builtin_amdgcn_mfma_f32_16x16x32_bf16(a1, aq[g][1], z, 0, 0, 0);
                G[t][g] = z;
            }
        }
        int qcH = (wid * 2 + (lr >> 3)) & 7;
        int qcW = lr & 7;
#pragma unroll
        for (int g = 0; g < 2; g++) {
            int qr = g * 64 + wid * 16 + lr;
#pragma unroll
            for (int r = 0; r < 4; r++) {
                int j = lg * 4 + r;
                int kd = g + 7 - j;
                if (kd >= 0 && kd < 8) bdT[kd][qr] = G[0][g][r];
                int kh = qcH + 7 - j;
                if (kh >= 0 && kh < 8) bhT[kh][qr] = G[1][g][r];
                int kw = qcW + 7 - j;
                if (kw >= 0 && kw < 8) bwT[kw][qr] = G[2][g][r];
            }
        }
    }
    __syncthreads();   // tables visible; tile-0 DMA drained (vmcnt in barrier)

    float m_run[2] = {-1e30f, -1e30f}, l_run[2] = {0.f, 0.f};
    f32x4 accO[2][4] = {};
    int sel = lg >> 1;
    const float SC = 0.125f * LOG2E;

#pragma unroll 1
    for (int kt = 0; kt < 8; kt++) {
        int cur = kt & 1;
        if (kt < 7) {
            size_t kAdv = (size_t)(kt + 1) * 64 * 2304;
            int vAdv = (kt + 1) * 64;
            GLDS16(kSrc0 + kAdv, &Ks[cur ^ 1][ldsOff0]);
            GLDS16(kSrc1 + kAdv, &Ks[cur ^ 1][ldsOff1]);
            GLDS16(vSrc0 + vAdv, &Vs[cur ^ 1][ldsOff0]);
            GLDS16(vSrc1 + vAdv, &Vs[cur ^ 1][ldsOff1]);
        }
        // S^T for both q-groups; K frags shared
        f32x4 sa[2][4];
#pragma unroll
        for (int kn = 0; kn < 4; kn++) {
            int krow = kn * 16 + lr;
            const short* kb_ = &Ks[cur][krow * 64];
            s16x8 ak0 = *(const s16x8*)&kb_[((lg ^ (krow & 7)) << 3)];
            s16x8 ak1 = *(const s16x8*)&kb_[(((4 + lg) ^ (krow & 7)) << 3)];
#pragma unroll
            for (int g = 0; g < 2; g++) {
                f32x4 z = {};
                z = __builtin_amdgcn_mfma_f32_16x16x32_bf16(ak0, aq[g][0], z, 0, 0, 0);
                z = __builtin_amdgcn_mfma_f32_16x16x32_bf16(ak1, aq[g][1], z, 0, 0, 0);
                sa[g][kn] = z;
            }
        }
        s32x4 pb[2][2];
#pragma unroll
        for (int g = 0; g < 2; g++) {
            int qr = g * 64 + wid * 16 + lr;
            float bdv = bdT[kt][qr];
            float bb[4], bwv[4];
#pragma unroll
            for (int kn = 0; kn < 4; kn++) bb[kn] = bdv + bhT[2 * kn + sel][qr];
#pragma unroll
            for (int r = 0; r < 4; r++) bwv[r] = bwT[4 * (lg & 1) + r][qr];
            float sv[4][4], mx = -1e30f;
#pragma unroll
            for (int kn = 0; kn < 4; kn++)
#pragma unroll
                for (int r = 0; r < 4; r++) {
                    float vv = sa[g][kn][r] * SC + (bb[kn] + bwv[r]);
                    sv[kn][r] = vv;
                    mx = fmaxf(mx, vv);
                }
            mx = fmaxf(mx, __shfl_xor(mx, 16));
            mx = fmaxf(mx, __shfl_xor(mx, 32));
            float nm = fmaxf(m_run[g], mx);
            float corr = exp2f(m_run[g] - nm);
            m_run[g] = nm;
            float p[4][4], tsum = 0.f;
#pragma unroll
            for (int kn = 0; kn < 4; kn++)
#pragma unroll
                for (int r = 0; r < 4; r++) {
                    float pv = exp2f(sv[kn][r] - nm);
                    p[kn][r] = pv; tsum += pv;
                }
            tsum += __shfl_xor(tsum, 16);
            tsum += __shfl_xor(tsum, 32);
            l_run[g] = l_run[g] * corr + tsum;
#pragma unroll
            for (int n = 0; n < 4; n++)
#pragma unroll
                for (int r = 0; r < 4; r++) accO[g][n][r] *= corr;
            unsigned u[4][2];
#pragma unroll
            for (int kn = 0; kn < 4; kn++) {
                u[kn][0] = cvt_pk_bf16(p[kn][0], p[kn][1]);
                u[kn][1] = cvt_pk_bf16(p[kn][2], p[kn][3]);
            }
#pragma unroll
            for (int s2 = 0; s2 < 2; s2++)
#pragma unroll
                for (int tp = 0; tp < 2; tp++) {
                    int src = (2 * (lg & 1) + tp) * 16 + lr;
#pragma unroll
                    for (int j = 0; j < 2; j++) {
                        int a0 = __shfl((int)u[2 * s2][j], src);
                        int a1 = __shfl((int)u[2 * s2 + 1][j], src);
                        pb[g][s2][tp * 2 + j] = sel ? a1 : a0;
                    }
                }
        }
        // PV: O^T; V frags shared across groups
#pragma unroll
        for (int s2 = 0; s2 < 2; s2++) {
            s16x8 pb0 = *(s16x8*)&pb[0][s2];
            s16x8 pb1 = *(s16x8*)&pb[1][s2];
#pragma unroll
            for (int n = 0; n < 4; n++) {
                int vrow = n * 16 + lr;
                s16x8 av = *(const s16x8*)&Vs[cur][vrow * 64 + (((s2 * 4 + lg) ^ (vrow & 7)) << 3)];
                accO[0][n] = __builtin_amdgcn_mfma_f32_16x16x32_bf16(av, pb0, accO[0][n], 0, 0, 0);
                accO[1][n] = __builtin_amdgcn_mfma_f32_16x16x32_bf16(av, pb1, accO[1][n], 0, 0, 0);
            }
        }
        __syncthreads();
    }
#pragma unroll
    for (int g = 0; g < 2; g++) {
        float inv = __builtin_amdgcn_rcpf(l_run[g]);
        int tok = win * 512 + qbase + g * 64 + wid * 16 + lr;
        short* orow = out + (size_t)tok * DIM + h * 64;
#pragma unroll
        for (int n = 0; n < 4; n++)
#pragma unroll
            for (int j = 0; j < 2; j++) {
                unsigned uo = cvt_pk_bf16(accO[g][n][2 * j] * inv, accO[g][n][2 * j + 1] * inv);
                *(unsigned*)&orow[n * 16 + 4 * lg + 2 * j] = uo;
            }
    }
}

// ---------------- launch ----------------
extern "C" void kernel_launch(void* const* d_in, const int* in_sizes, int n_in,
                              void* d_out, int out_size, void* d_ws, size_t ws_size,
                              hipStream_t stream) {
    const float* x      = (const float*)d_in[0];
    const float* w_qkv  = (const float*)d_in[1];
    const float* b_qkv  = (const float*)d_in[2];
    const float* w_proj = (const float*)d_in[3];
    const float* b_proj = (const float*)d_in[4];
    const float* rpd    = (const float*)d_in[5];
    const float* rph    = (const float*)d_in[6];
    const float* rpw    = (const float*)d_in[7];
    const float* n1w    = (const float*)d_in[8];
    const float* n1b    = (const float*)d_in[9];
    const float* n2w    = (const float*)d_in[10];
    const float* n2b    = (const float*)d_in[11];
    const float* w1     = (const float*)d_in[12];
    const float* b1     = (const float*)d_in[13];
    const float* w2     = (const float*)d_in[14];
    const float* b2     = (const float*)d_in[15];
    float* out = (float*)d_out;
    char* ws = (char*)d_ws;
    size_t off = 0;
    auto alloc = [&](size_t bytes) { void* p = ws + off; off += (bytes + 255) & ~255ULL; return p; };
    short* wqkvT  = (short*)alloc((size_t)2304 * 768 * 2);
    short* wprojT = (short*)alloc((size_t)768 * 768 * 2);
    short* w1T    = (short*)alloc((size_t)3072 * 768 * 2);
    short* w2T    = (short*)alloc((size_t)768 * 3072 * 2);
    short* xn1    = (short*)alloc((size_t)8192 * 768 * 2);   // reused as attn-out
    short* qkvC   = (short*)alloc((size_t)8192 * 2304 * 2);
    short* vtb    = (short*)alloc((size_t)192 * 64 * 512 * 2);
    short* xn2    = (short*)alloc((size_t)8192 * 768 * 2);
    short* hid    = (short*)alloc((size_t)8192 * 3072 * 2);
    short* attnout = xn1;

    transpose_cvt<<<dim3(2304 / 32, 768 / 32), 256, 0, stream>>>(w_qkv, wqkvT, 768, 2304);
    transpose_cvt<<<dim3(768 / 32, 768 / 32), 256, 0, stream>>>(w_proj, wprojT, 768, 768);
    transpose_cvt<<<dim3(3072 / 32, 768 / 32), 256, 0, stream>>>(w1, w1T, 768, 3072);
    transpose_cvt<<<dim3(768 / 32, 3072 / 32), 256, 0, stream>>>(w2, w2T, 3072, 768);

    ln_kernel<1><<<8192, 256, 0, stream>>>(x, n1w, n1b, xn1);
    gemm_kernel<EPI_C, 768, 2304><<<dim3(18, 64), 256, 0, stream>>>(
        xn1, wqkvT, b_qkv, nullptr, nullptr, qkvC);
    repack_vt<<<dim3(8, 192), 256, 0, stream>>>(qkvC, vtb);
    attn_kernel<<<dim3(4, 192), 256, 0, stream>>>(qkvC, vtb, rpd, rph, rpw, attnout);
    gemm_kernel<EPI_PROJ, 768, 768><<<dim3(6, 64), 256, 0, stream>>>(
        attnout, wprojT, b_proj, x, out, nullptr);
    ln_kernel<0><<<8192, 256, 0, stream>>>(out, n2w, n2b, xn2);
    gemm_kernel<EPI_GELU, 768, 3072><<<dim3(24, 64), 256, 0, stream>>>(
        xn2, w1T, b1, nullptr, nullptr, hid);
    gemm_kernel<EPI_MLP2, 3072, 768><<<dim3(6, 64), 256, 0, stream>>>(
        hid, w2T, b2, nullptr, out, nullptr);
}

// Round 7
// 256.711 us; speedup vs baseline: 4.5283x; 1.1711x over previous
//
#include <hip/hip_runtime.h>
#include <hip/hip_bf16.h>
#include <math.h>

typedef short s16x8 __attribute__((ext_vector_type(8)));
typedef float f32x4 __attribute__((ext_vector_type(4)));
typedef int   s32x4 __attribute__((ext_vector_type(4)));

#define DIM 768
#define HEADS 12

static __device__ __forceinline__ short f2bf(float x) {
    union { float f; unsigned u; } v; v.f = x;
    unsigned r = (v.u + 0x7FFF + ((v.u >> 16) & 1)) >> 16;
    return (short)r;
}
static __device__ __forceinline__ float bf2f(short x) {
    union { unsigned u; float f; } v;
    v.u = ((unsigned)(unsigned short)x) << 16;
    return v.f;
}
// packed f32x2 -> bf16x2 (RNE), single HW instr; no builtin on gfx950
static __device__ __forceinline__ unsigned cvt_pk_bf16(float lo, float hi) {
    unsigned r;
    asm("v_cvt_pk_bf16_f32 %0, %1, %2" : "=v"(r) : "v"(lo), "v"(hi));
    return r;
}

// async global->LDS, 16B per lane, wave-uniform LDS base + lane*16
#define GLDS16(g, l) __builtin_amdgcn_global_load_lds( \
    (__attribute__((address_space(1))) void*)(g), \
    (__attribute__((address_space(3))) void*)(l), 16, 0, 0)

// partitioned token t (win*512+n) -> natural token index in [0, 8192)
static __device__ __forceinline__ int nat_row(int t) {
    int w = t >> 9, n = t & 511;
    int b = w >> 3, dO = (w >> 2) & 1, hO = (w >> 1) & 1, wO = w & 1;
    int di = n >> 6, hi = (n >> 3) & 7, wi = n & 7;
    int Dd = dO * 8 + di, Hh = hO * 8 + hi, Ww = wO * 8 + wi;
    return ((b * 16 + Dd) * 16 + Hh) * 16 + Ww;
}

// ---------------- weight transpose + fp32->bf16 ----------------
__global__ __launch_bounds__(256) void transpose_cvt(
    const float* __restrict__ in, short* __restrict__ out, int K, int N) {
    __shared__ float tile[32][33];
    int n0 = blockIdx.x * 32, k0 = blockIdx.y * 32;
    int tx = threadIdx.x & 31, ty = threadIdx.x >> 5;
#pragma unroll
    for (int j = 0; j < 4; j++) {
        int r = ty + j * 8;
        tile[r][tx] = in[(size_t)(k0 + r) * N + n0 + tx];
    }
    __syncthreads();
#pragma unroll
    for (int j = 0; j < 4; j++) {
        int r = ty + j * 8;
        out[(size_t)(n0 + r) * K + k0 + tx] = f2bf(tile[tx][r]);
    }
}

// ---------------- layernorm (PART=1: window-partition remap of input row) ----
template<int PART>
__global__ __launch_bounds__(256) void ln_kernel(
    const float* __restrict__ x, const float* __restrict__ gw,
    const float* __restrict__ gb, short* __restrict__ out) {
    int t = blockIdx.x;
    int row = PART ? nat_row(t) : t;
    const float* xr = x + (size_t)row * DIM;
    float v0 = xr[threadIdx.x], v1 = xr[threadIdx.x + 256], v2 = xr[threadIdx.x + 512];
    float s1 = v0 + v1 + v2;
    float s2 = v0 * v0 + v1 * v1 + v2 * v2;
#pragma unroll
    for (int o = 32; o > 0; o >>= 1) { s1 += __shfl_down(s1, o); s2 += __shfl_down(s2, o); }
    __shared__ float ws1[4], ws2[4];
    int wid = threadIdx.x >> 6, lane = threadIdx.x & 63;
    if (lane == 0) { ws1[wid] = s1; ws2[wid] = s2; }
    __syncthreads();
    s1 = ws1[0] + ws1[1] + ws1[2] + ws1[3];
    s2 = ws2[0] + ws2[1] + ws2[2] + ws2[3];
    float mean = s1 * (1.f / DIM);
    float var = s2 * (1.f / DIM) - mean * mean;
    float inv = rsqrtf(var + 1e-5f);
    short* orow = out + (size_t)t * DIM;
    orow[threadIdx.x]       = f2bf((v0 - mean) * inv * gw[threadIdx.x]       + gb[threadIdx.x]);
    orow[threadIdx.x + 256] = f2bf((v1 - mean) * inv * gw[threadIdx.x + 256] + gb[threadIdx.x + 256]);
    orow[threadIdx.x + 512] = f2bf((v2 - mean) * inv * gw[threadIdx.x + 512] + gb[threadIdx.x + 512]);
}

// ---------------- GEMM: C[M,N] = A[M,K] (bf16) @ BT[N,K]^T (bf16) -----------
// 2-phase double-buffered pipeline: STAGE(t+1) issued BEFORE compute(t), one
// barrier per K-tile (T3-minimum). 1-D grid + bijective XCD-chunk swizzle so
// blocks sharing the A-panel land on the same XCD L2 (T1). BM=128, BK=64;
// BN templated (128 for big-N, 64 for N=768 -> 3 blocks/CU, grid 768).
enum { EPI_C = 0, EPI_PROJ = 1, EPI_GELU = 2, EPI_MLP2 = 3 };

template<int EPI, int K, int N, int BN>
__global__ __launch_bounds__(256) void gemm_kernel(
    const short* __restrict__ A, const short* __restrict__ BT,
    const float* __restrict__ bias,
    const float* __restrict__ x_in, float* __restrict__ out_f,
    short* __restrict__ out_b) {
    constexpr int GX = N / BN;        // tiles along N
    constexpr int NW = BN / 32;       // B frags per wave / B stage-chunks per thread
    constexpr int NT = K / 64;
    __shared__ short As[2][128 * 64];
    __shared__ short Bs[2][BN * 64];
    int flat = blockIdx.x;
    int cpx = gridDim.x >> 3;                      // grid divisible by 8
    int swz = (flat & 7) * cpx + (flat >> 3);      // XCD-chunk remap
    int tile_n = swz % GX, tile_m = swz / GX;
    int tid = threadIdx.x;
    int wid = tid >> 6, lane = tid & 63, lr = lane & 15, lg = lane >> 4;
    int wr = wid >> 1, wc = wid & 1;
    f32x4 acc[4][NW] = {};
    const short* Arow = A + (size_t)(tile_m * 128) * K;
    const short* Brow = BT + (size_t)(tile_n * BN) * K;
    // staging: chunk c = i*256 + tid; row = c>>3, slot = c&7
    // source slot pre-swizzled: (lane&7) ^ (row&7); row&7 == (tid>>3)&7
    int swzS = ((lane & 7) ^ ((tid >> 3) & 7)) * 8;
    const short* gA[4]; int ldsOA[4];
#pragma unroll
    for (int i = 0; i < 4; i++) {
        int row = (i * 256 + tid) >> 3;
        gA[i] = Arow + (size_t)row * K + swzS;
        ldsOA[i] = (i * 256 + wid * 64) * 8;
    }
    const short* gB[NW]; int ldsOB[NW];
#pragma unroll
    for (int i = 0; i < NW; i++) {
        int row = (i * 256 + tid) >> 3;
        gB[i] = Brow + (size_t)row * K + swzS;
        ldsOB[i] = (i * 256 + wid * 64) * 8;
    }
    auto stage = [&](int buf, int k0) {
#pragma unroll
        for (int i = 0; i < 4; i++) GLDS16(gA[i] + k0, &As[buf][ldsOA[i]]);
#pragma unroll
        for (int i = 0; i < NW; i++) GLDS16(gB[i] + k0, &Bs[buf][ldsOB[i]]);
    };
    stage(0, 0);
    __syncthreads();
#pragma unroll 1
    for (int t = 0; t < NT; t++) {
        int cur = t & 1;
        if (t + 1 < NT) stage(cur ^ 1, (t + 1) * 64);   // prefetch flies under MFMA
#pragma unroll
        for (int h = 0; h < 2; h++) {
            s16x8 af[4], bfr[NW];
#pragma unroll
            for (int m = 0; m < 4; m++) {
                int row = wr * 64 + m * 16 + lr;
                af[m] = *(const s16x8*)&As[cur][row * 64 + (((h * 4 + lg) ^ (lr & 7)) << 3)];
            }
#pragma unroll
            for (int n = 0; n < NW; n++) {
                int row = wc * (BN / 2) + n * 16 + lr;
                bfr[n] = *(const s16x8*)&Bs[cur][row * 64 + (((h * 4 + lg) ^ (lr & 7)) << 3)];
            }
#pragma unroll
            for (int m = 0; m < 4; m++)
#pragma unroll
                for (int n = 0; n < NW; n++)
                    acc[m][n] = __builtin_amdgcn_mfma_f32_16x16x32_bf16(af[m], bfr[n], acc[m][n], 0, 0, 0);
        }
        __syncthreads();   // drains prefetch (vmcnt) + compute's lgkm
    }
#pragma unroll
    for (int m = 0; m < 4; m++)
#pragma unroll
        for (int n = 0; n < NW; n++)
#pragma unroll
            for (int r = 0; r < 4; r++) {
                int row = tile_m * 128 + wr * 64 + m * 16 + lg * 4 + r;
                int col = tile_n * BN + wc * (BN / 2) + n * 16 + lr;
                float v = acc[m][n][r] + bias[col];
                if (EPI == EPI_C) {
                    out_b[(size_t)row * N + col] = f2bf(v);
                } else if (EPI == EPI_PROJ) {
                    int nr = nat_row(row);
                    out_f[(size_t)nr * DIM + col] = v + x_in[(size_t)nr * DIM + col];
                } else if (EPI == EPI_GELU) {
                    // tanh-form GELU (abs err ~1e-3 vs erf; native exp)
                    float u = v * (0.7978845608f + 0.0356774081f * v * v);
                    float e = __expf(2.f * u);
                    float g = v - v * __builtin_amdgcn_rcpf(1.f + e);
                    out_b[(size_t)row * (size_t)N + col] = f2bf(g);
                } else { // EPI_MLP2
                    out_f[(size_t)row * DIM + col] += v;
                }
            }
}

// ---------------- V repack: qkv[t, 1536+h*64+d] -> vt[wh][d][tok] ----------
__global__ __launch_bounds__(256) void repack_vt(
    const short* __restrict__ qkv, short* __restrict__ vt) {
    __shared__ short tile[64][72];
    int ntb = blockIdx.x, wh = blockIdx.y;
    int win = wh / HEADS, h = wh % HEADS;
    const short* vbase = qkv + (size_t)(win * 512 + ntb * 64) * 2304 + 1536 + h * 64;
    int tid = threadIdx.x;
#pragma unroll
    for (int p = 0; p < 2; p++) {
        int idx = tid + p * 256;
        int tok = idx >> 3, vc = idx & 7;
        s16x8 v = *(const s16x8*)&vbase[(size_t)tok * 2304 + vc * 8];
#pragma unroll
        for (int j = 0; j < 8; j++) tile[vc * 8 + j][tok] = v[j];
    }
    __syncthreads();
#pragma unroll
    for (int p = 0; p < 2; p++) {
        int idx = tid + p * 256;
        int d = idx >> 3, vc = idx & 7;
        s16x8 o = *(const s16x8*)&tile[d][vc * 8];
        *(s16x8*)&vt[((size_t)wh * 64 + d) * 512 + ntb * 64 + vc * 8] = o;
    }
}

// ---------------- attention: q-tile 128 (2 groups/wave), MFMA bias prologue -
__global__ __launch_bounds__(256) void attn_kernel(
    const short* __restrict__ qkv, const short* __restrict__ vt,
    const float* __restrict__ rpd, const float* __restrict__ rph,
    const float* __restrict__ rpw, short* __restrict__ out) {
    __shared__ float bdT[8][128], bhT[8][128], bwT[8][128];  // log2-domain
    __shared__ short Rs[48 * 64];
    __shared__ short Ks[2][64 * 64];
    __shared__ short Vs[2][64 * 64];
    int qt2 = blockIdx.x;  // 0..3 (q rows qt2*128 .. +127)
    int wh = blockIdx.y;   // 0..191
    int win = wh / HEADS, h = wh % HEADS;
    int qbase = qt2 * 128;
    const short* qp = qkv + (size_t)(win * 512) * 2304 + h * 64;  // row stride 2304
    const short* kp = qp + 768;
    const short* vp = vt + (size_t)wh * 64 * 512;
    int tid = threadIdx.x, wid = tid >> 6, lane = tid & 63, lr = lane & 15, lg = lane >> 4;
    const float LOG2E = 1.4426950408889634f;

    s16x8 aq[2][2];
#pragma unroll
    for (int g = 0; g < 2; g++) {
        size_t qoff = (size_t)(qbase + g * 64 + wid * 16 + lr) * 2304;
        aq[g][0] = *(const s16x8*)&qp[qoff + lg * 8];
        aq[g][1] = *(const s16x8*)&qp[qoff + 32 + lg * 8];
    }

    for (int i = tid; i < 48 * 64; i += 256) {
        int row = i >> 6, c = i & 63;
        float v = 0.f;
        if (row < 9)                     v = rpd[(qt2 * 2 + row) * 64 + c];
        else if (row >= 16 && row < 31)  v = rph[(row - 16) * 64 + c];
        else if (row >= 32 && row < 47)  v = rpw[(row - 32) * 64 + c];
        Rs[row * 64 + ((((c >> 3) ^ (row & 7)) << 3) | (c & 7))] = f2bf(v * LOG2E);
    }
    __syncthreads();

    int row0 = wid * 8 + (lane >> 3);
    int swz = ((lane & 7) ^ (row0 & 7)) * 8;
    const short* kSrc0 = kp + (size_t)row0 * 2304 + swz;
    const short* kSrc1 = kp + (size_t)(row0 + 32) * 2304 + swz;
    const short* vSrc0 = vp + (size_t)row0 * 512 + swz;
    const short* vSrc1 = vp + (size_t)(row0 + 32) * 512 + swz;
    int ldsOff0 = wid * 512, ldsOff1 = 2048 + wid * 512;

    GLDS16(kSrc0, &Ks[0][ldsOff0]);
    GLDS16(kSrc1, &Ks[0][ldsOff1]);
    GLDS16(vSrc0, &Vs[0][ldsOff0]);
    GLDS16(vSrc1, &Vs[0][ldsOff1]);

    {
        f32x4 G[3][2];
#pragma unroll
        for (int t = 0; t < 3; t++) {
            int arow = t * 16 + lr;
            s16x8 a0 = *(const s16x8*)&Rs[arow * 64 + ((lg ^ (arow & 7)) << 3)];
            s16x8 a1 = *(const s16x8*)&Rs[arow * 64 + (((4 + lg) ^ (arow & 7)) << 3)];
#pragma unroll
            for (int g = 0; g < 2; g++) {
                f32x4 z = {};
                z = __builtin_amdgcn_mfma_f32_16x16x32_bf16(a0, aq[g][0], z, 0, 0, 0);
                z = __builtin_amdgcn_mfma_f32_16x16x32_bf16(a1, aq[g][1], z, 0, 0, 0);
                G[t][g] = z;
            }
        }
        int qcH = (wid * 2 + (lr >> 3)) & 7;
        int qcW = lr & 7;
#pragma unroll
        for (int g = 0; g < 2; g++) {
            int qr = g * 64 + wid * 16 + lr;
#pragma unroll
            for (int r = 0; r < 4; r++) {
                int j = lg * 4 + r;
                int kd = g + 7 - j;
                if (kd >= 0 && kd < 8) bdT[kd][qr] = G[0][g][r];
                int kh = qcH + 7 - j;
                if (kh >= 0 && kh < 8) bhT[kh][qr] = G[1][g][r];
                int kw = qcW + 7 - j;
                if (kw >= 0 && kw < 8) bwT[kw][qr] = G[2][g][r];
            }
        }
    }
    __syncthreads();

    float m_run[2] = {-1e30f, -1e30f}, l_run[2] = {0.f, 0.f};
    f32x4 accO[2][4] = {};
    int sel = lg >> 1;
    const float SC = 0.125f * LOG2E;

#pragma unroll 1
    for (int kt = 0; kt < 8; kt++) {
        int cur = kt & 1;
        if (kt < 7) {
            size_t kAdv = (size_t)(kt + 1) * 64 * 2304;
            int vAdv = (kt + 1) * 64;
            GLDS16(kSrc0 + kAdv, &Ks[cur ^ 1][ldsOff0]);
            GLDS16(kSrc1 + kAdv, &Ks[cur ^ 1][ldsOff1]);
            GLDS16(vSrc0 + vAdv, &Vs[cur ^ 1][ldsOff0]);
            GLDS16(vSrc1 + vAdv, &Vs[cur ^ 1][ldsOff1]);
        }
        f32x4 sa[2][4];
#pragma unroll
        for (int kn = 0; kn < 4; kn++) {
            int krow = kn * 16 + lr;
            const short* kb_ = &Ks[cur][krow * 64];
            s16x8 ak0 = *(const s16x8*)&kb_[((lg ^ (krow & 7)) << 3)];
            s16x8 ak1 = *(const s16x8*)&kb_[(((4 + lg) ^ (krow & 7)) << 3)];
#pragma unroll
            for (int g = 0; g < 2; g++) {
                f32x4 z = {};
                z = __builtin_amdgcn_mfma_f32_16x16x32_bf16(ak0, aq[g][0], z, 0, 0, 0);
                z = __builtin_amdgcn_mfma_f32_16x16x32_bf16(ak1, aq[g][1], z, 0, 0, 0);
                sa[g][kn] = z;
            }
        }
        s32x4 pb[2][2];
#pragma unroll
        for (int g = 0; g < 2; g++) {
            int qr = g * 64 + wid * 16 + lr;
            float bdv = bdT[kt][qr];
            float bb[4], bwv[4];
#pragma unroll
            for (int kn = 0; kn < 4; kn++) bb[kn] = bdv + bhT[2 * kn + sel][qr];
#pragma unroll
            for (int r = 0; r < 4; r++) bwv[r] = bwT[4 * (lg & 1) + r][qr];
            float sv[4][4], mx = -1e30f;
#pragma unroll
            for (int kn = 0; kn < 4; kn++)
#pragma unroll
                for (int r = 0; r < 4; r++) {
                    float vv = sa[g][kn][r] * SC + (bb[kn] + bwv[r]);
                    sv[kn][r] = vv;
                    mx = fmaxf(mx, vv);
                }
            mx = fmaxf(mx, __shfl_xor(mx, 16));
            mx = fmaxf(mx, __shfl_xor(mx, 32));
            float nm = fmaxf(m_run[g], mx);
            float corr = exp2f(m_run[g] - nm);
            m_run[g] = nm;
            float p[4][4], tsum = 0.f;
#pragma unroll
            for (int kn = 0; kn < 4; kn++)
#pragma unroll
                for (int r = 0; r < 4; r++) {
                    float pv = exp2f(sv[kn][r] - nm);
                    p[kn][r] = pv; tsum += pv;
                }
            tsum += __shfl_xor(tsum, 16);
            tsum += __shfl_xor(tsum, 32);
            l_run[g] = l_run[g] * corr + tsum;
#pragma unroll
            for (int n = 0; n < 4; n++)
#pragma unroll
                for (int r = 0; r < 4; r++) accO[g][n][r] *= corr;
            unsigned u[4][2];
#pragma unroll
            for (int kn = 0; kn < 4; kn++) {
                u[kn][0] = cvt_pk_bf16(p[kn][0], p[kn][1]);
                u[kn][1] = cvt_pk_bf16(p[kn][2], p[kn][3]);
            }
#pragma unroll
            for (int s2 = 0; s2 < 2; s2++)
#pragma unroll
                for (int tp = 0; tp < 2; tp++) {
                    int src = (2 * (lg & 1) + tp) * 16 + lr;
#pragma unroll
                    for (int j = 0; j < 2; j++) {
                        int a0 = __shfl((int)u[2 * s2][j], src);
                        int a1 = __shfl((int)u[2 * s2 + 1][j], src);
                        pb[g][s2][tp * 2 + j] = sel ? a1 : a0;
                    }
                }
        }
#pragma unroll
        for (int s2 = 0; s2 < 2; s2++) {
            s16x8 pb0 = *(s16x8*)&pb[0][s2];
            s16x8 pb1 = *(s16x8*)&pb[1][s2];
#pragma unroll
            for (int n = 0; n < 4; n++) {
                int vrow = n * 16 + lr;
                s16x8 av = *(const s16x8*)&Vs[cur][vrow * 64 + (((s2 * 4 + lg) ^ (vrow & 7)) << 3)];
                accO[0][n] = __builtin_amdgcn_mfma_f32_16x16x32_bf16(av, pb0, accO[0][n], 0, 0, 0);
                accO[1][n] = __builtin_amdgcn_mfma_f32_16x16x32_bf16(av, pb1, accO[1][n], 0, 0, 0);
            }
        }
        __syncthreads();
    }
#pragma unroll
    for (int g = 0; g < 2; g++) {
        float inv = __builtin_amdgcn_rcpf(l_run[g]);
        int tok = win * 512 + qbase + g * 64 + wid * 16 + lr;
        short* orow = out + (size_t)tok * DIM + h * 64;
#pragma unroll
        for (int n = 0; n < 4; n++)
#pragma unroll
            for (int j = 0; j < 2; j++) {
                unsigned uo = cvt_pk_bf16(accO[g][n][2 * j] * inv, accO[g][n][2 * j + 1] * inv);
                *(unsigned*)&orow[n * 16 + 4 * lg + 2 * j] = uo;
            }
    }
}

// ---------------- launch ----------------
extern "C" void kernel_launch(void* const* d_in, const int* in_sizes, int n_in,
                              void* d_out, int out_size, void* d_ws, size_t ws_size,
                              hipStream_t stream) {
    const float* x      = (const float*)d_in[0];
    const float* w_qkv  = (const float*)d_in[1];
    const float* b_qkv  = (const float*)d_in[2];
    const float* w_proj = (const float*)d_in[3];
    const float* b_proj = (const float*)d_in[4];
    const float* rpd    = (const float*)d_in[5];
    const float* rph    = (const float*)d_in[6];
    const float* rpw    = (const float*)d_in[7];
    const float* n1w    = (const float*)d_in[8];
    const float* n1b    = (const float*)d_in[9];
    const float* n2w    = (const float*)d_in[10];
    const float* n2b    = (const float*)d_in[11];
    const float* w1     = (const float*)d_in[12];
    const float* b1     = (const float*)d_in[13];
    const float* w2     = (const float*)d_in[14];
    const float* b2     = (const float*)d_in[15];
    float* out = (float*)d_out;
    char* ws = (char*)d_ws;
    size_t off = 0;
    auto alloc = [&](size_t bytes) { void* p = ws + off; off += (bytes + 255) & ~255ULL; return p; };
    short* wqkvT  = (short*)alloc((size_t)2304 * 768 * 2);
    short* wprojT = (short*)alloc((size_t)768 * 768 * 2);
    short* w1T    = (short*)alloc((size_t)3072 * 768 * 2);
    short* w2T    = (short*)alloc((size_t)768 * 3072 * 2);
    short* xn1    = (short*)alloc((size_t)8192 * 768 * 2);   // reused as attn-out
    short* qkvC   = (short*)alloc((size_t)8192 * 2304 * 2);
    short* vtb    = (short*)alloc((size_t)192 * 64 * 512 * 2);
    short* xn2    = (short*)alloc((size_t)8192 * 768 * 2);
    short* hid    = (short*)alloc((size_t)8192 * 3072 * 2);
    short* attnout = xn1;

    transpose_cvt<<<dim3(2304 / 32, 768 / 32), 256, 0, stream>>>(w_qkv, wqkvT, 768, 2304);
    transpose_cvt<<<dim3(768 / 32, 768 / 32), 256, 0, stream>>>(w_proj, wprojT, 768, 768);
    transpose_cvt<<<dim3(3072 / 32, 768 / 32), 256, 0, stream>>>(w1, w1T, 768, 3072);
    transpose_cvt<<<dim3(768 / 32, 3072 / 32), 256, 0, stream>>>(w2, w2T, 3072, 768);

    ln_kernel<1><<<8192, 256, 0, stream>>>(x, n1w, n1b, xn1);
    gemm_kernel<EPI_C, 768, 2304, 128><<<18 * 64, 256, 0, stream>>>(
        xn1, wqkvT, b_qkv, nullptr, nullptr, qkvC);
    repack_vt<<<dim3(8, 192), 256, 0, stream>>>(qkvC, vtb);
    attn_kernel<<<dim3(4, 192), 256, 0, stream>>>(qkvC, vtb, rpd, rph, rpw, attnout);
    gemm_kernel<EPI_PROJ, 768, 768, 64><<<12 * 64, 256, 0, stream>>>(
        attnout, wprojT, b_proj, x, out, nullptr);
    ln_kernel<0><<<8192, 256, 0, stream>>>(out, n2w, n2b, xn2);
    gemm_kernel<EPI_GELU, 768, 3072, 128><<<24 * 64, 256, 0, stream>>>(
        xn2, w1T, b1, nullptr, nullptr, hid);
    gemm_kernel<EPI_MLP2, 3072, 768, 64><<<12 * 64, 256, 0, stream>>>(
        hid, w2T, b2, nullptr, out, nullptr);
}